// Round 15
// baseline (490.740 us; speedup 1.0000x reference)
//
#include <hip/hip_runtime.h>
#include <math.h>

#define HID 256
#define TD 32
#define NL 3
#define C1DIM 128
#define OUTDIM 2
#define QKVW 768

using half8  = __attribute__((ext_vector_type(8))) _Float16;
using half2v = __attribute__((ext_vector_type(2))) _Float16;
using f32x4  = __attribute__((ext_vector_type(4))) float;

typedef __attribute__((address_space(1))) void gbl_void_t;
typedef __attribute__((address_space(3))) void lds_void_t;

__device__ __forceinline__ void load16_to_lds(const void* g, void* l) {
  __builtin_amdgcn_global_load_lds((const gbl_void_t*)g, (lds_void_t*)l, 16, 0, 0);
}

__device__ __forceinline__ float dot8h(half8 a, half8 b, float acc) {
#if __has_builtin(__builtin_amdgcn_fdot2)
  union { half8 v; half2v h2[4]; } ua, ub;
  ua.v = a; ub.v = b;
#pragma unroll
  for (int j = 0; j < 4; ++j) acc = __builtin_amdgcn_fdot2(ua.h2[j], ub.h2[j], acc, false);
  return acc;
#else
#pragma unroll
  for (int j = 0; j < 8; ++j) acc += (float)a[j] * (float)b[j];
  return acc;
#endif
}

// ---------- setup: ts min/max (single block) + zero deg ----------
__global__ __launch_bounds__(1024) void k_tsmm(const float* __restrict__ ts,
                                               float* __restrict__ mmf,
                                               int* __restrict__ deg, int n) {
  int t = threadIdx.x;
  float lmin = INFINITY, lmax = -INFINITY;
  for (int i = t; i < n; i += 1024) {
    float v = ts[i];
    lmin = fminf(lmin, v);
    lmax = fmaxf(lmax, v);
    deg[i] = 0;
  }
#pragma unroll
  for (int off = 32; off >= 1; off >>= 1) {
    lmin = fminf(lmin, __shfl_xor(lmin, off));
    lmax = fmaxf(lmax, __shfl_xor(lmax, off));
  }
  __shared__ float wmin[16], wmax[16];
  int lane = t & 63, w = t >> 6;
  if (lane == 0) { wmin[w] = lmin; wmax[w] = lmax; }
  __syncthreads();
  if (t == 0) {
    float a = INFINITY, b = -INFINITY;
    for (int i = 0; i < 16; ++i) { a = fminf(a, wmin[i]); b = fmaxf(b, wmax[i]); }
    mmf[0] = a; mmf[1] = b;
  }
}

// ---------- merged time encoding + x conversion ----------
__global__ void k_enc(const float* __restrict__ ts, const float* __restrict__ freq,
                      const float* __restrict__ mmf, const float* __restrict__ x,
                      _Float16* __restrict__ tfh, _Float16* __restrict__ xh, int n) {
  int idx = blockIdx.x * blockDim.x + threadIdx.x;
  int nt = n * TD;
  if (idx < nt) {
    int node = idx >> 5, j = idx & 31;
    float t = (ts[node] - mmf[0]) / (mmf[1] - mmf[0] + 1e-8f);
    float w = t * freq[j & 15];
    tfh[idx] = (_Float16)((j < 16) ? cosf(w) : sinf(w));
  } else if (idx < nt + n * 32) {
    int i2 = idx - nt;
    xh[i2] = (_Float16)x[i2];
  }
}

// ---------- LDS-tiled weight prep: coalesced transposes + bias fuse ----------
#define NB_QKV (NL * 9 * 12)   // k-tiles 288/32 x n-tiles 768/64
#define NB_O   (NL * 8 * 4)    // 256/32 x 256/64
#define NB_B   9               // NL*768 / 256

__global__ __launch_bounds__(256) void k_prep2(
    const float* __restrict__ qW, const float* __restrict__ kW,
    const float* __restrict__ vW, const float* __restrict__ oW,
    const float* __restrict__ qb, const float* __restrict__ kb,
    const float* __restrict__ vb,
    _Float16* __restrict__ qkvWt, float* __restrict__ qkvb,
    _Float16* __restrict__ oWt) {
  __shared__ _Float16 lds[32][65];
  int bid = blockIdx.x;
  int t = threadIdx.x;
  const int KQ = HID + TD;  // 288

  if (bid < NB_QKV) {
    int l = bid / 108;
    int rem = bid - l * 108;
    int kt = rem / 12, ntile = rem - kt * 12;
    int k0 = kt * 32, n0 = ntile * 64;
#pragma unroll
    for (int it = 0; it < 8; ++it) {
      int i = it * 256 + t;
      int kk = i >> 6, nn = i & 63;
      int k = k0 + kk, nrow = n0 + nn;
      float v;
      if (nrow < 256)      v = qW[(size_t)l * KQ * HID + (size_t)k * HID + nrow];
      else if (nrow < 512) v = kW[(size_t)l * KQ * HID + (size_t)k * HID + (nrow - 256)];
      else                 v = (k < HID) ? vW[(size_t)l * HID * HID + (size_t)k * HID + (nrow - 512)] : 0.f;
      lds[kk][nn] = (_Float16)v;
    }
    __syncthreads();
    {
      int nn = t >> 2, kq = (t & 3) * 8;
      _Float16* dst = qkvWt + (size_t)l * QKVW * KQ + (size_t)(n0 + nn) * KQ + k0 + kq;
      half8 v;
#pragma unroll
      for (int j = 0; j < 8; ++j) v[j] = lds[kq + j][nn];
      *(half8*)dst = v;
    }
    return;
  }
  bid -= NB_QKV;

  if (bid < NB_O) {
    int l = bid / 32;
    int rem = bid - l * 32;
    int kt = rem / 4, ntile = rem - kt * 4;
    int k0 = kt * 32, n0 = ntile * 64;
#pragma unroll
    for (int it = 0; it < 8; ++it) {
      int i = it * 256 + t;
      int kk = i >> 6, nn = i & 63;
      lds[kk][nn] = (_Float16)oW[(size_t)l * HID * HID + (size_t)(k0 + kk) * HID + n0 + nn];
    }
    __syncthreads();
    {
      int nn = t >> 2, kq = (t & 3) * 8;
      _Float16* dst = oWt + (size_t)l * HID * HID + (size_t)(n0 + nn) * HID + k0 + kq;
      half8 v;
#pragma unroll
      for (int j = 0; j < 8; ++j) v[j] = lds[kq + j][nn];
      *(half8*)dst = v;
    }
    return;
  }
  bid -= NB_O;

  {
    int idx = bid * 256 + t;
    if (idx < NL * QKVW) {
      int l = idx / QKVW;
      int j = idx - l * QKVW;
      float v;
      if (j < 256)      v = qb[l * HID + j];
      else if (j < 512) v = kb[l * HID + (j - 256)];
      else              v = vb[l * HID + (j - 512)];
      qkvb[idx] = v;
    }
  }
}

// ---------- layer-0 fold: WcT[768][64] = [inW@W0_h ; W0_tf]^T, bc = qkvb0 + inb@W0_h ----------
__global__ __launch_bounds__(256) void k_fold(const float* __restrict__ inW,
                                              const float* __restrict__ inb,
                                              const float* __restrict__ qW,
                                              const float* __restrict__ kW,
                                              const float* __restrict__ vW,
                                              const float* __restrict__ qb,
                                              const float* __restrict__ kb,
                                              const float* __restrict__ vb,
                                              _Float16* __restrict__ WcT,
                                              float* __restrict__ bc) {
  int idx = blockIdx.x * 256 + threadIdx.x;
  if (idx >= 65 * QKVW) return;
  int j = idx / QKVW;
  int nrow = idx - j * QKVW;
  auto W0 = [&](int c, int nr) -> float {
    if (nr < 256)      return qW[(size_t)c * HID + nr];
    else if (nr < 512) return kW[(size_t)c * HID + (nr - 256)];
    else               return vW[(size_t)c * HID + (nr - 512)];
  };
  if (j < 32) {
    float acc = 0.f;
    for (int c = 0; c < 256; ++c) acc += inW[j * HID + c] * W0(c, nrow);
    WcT[(size_t)nrow * 64 + j] = (_Float16)acc;
  } else if (j < 64) {
    int r = 256 + (j - 32);
    float v = 0.f;
    if (nrow < 256)      v = qW[(size_t)r * HID + nrow];
    else if (nrow < 512) v = kW[(size_t)r * HID + (nrow - 256)];
    WcT[(size_t)nrow * 64 + j] = (_Float16)v;
  } else {
    float acc;
    if (nrow < 256)      acc = qb[nrow];
    else if (nrow < 512) acc = kb[nrow - 256];
    else                 acc = vb[nrow - 512];
    for (int c = 0; c < 256; ++c) acc += inb[c] * W0(c, nrow);
    bc[nrow] = acc;
  }
}

__global__ void k_count(const int* __restrict__ dst, int* deg, int e) {
  int i = blockIdx.x * blockDim.x + threadIdx.x;
  if (i < e) atomicAdd(&deg[dst[i]], 1);
}

// ---------- 3-kernel scan ----------
__global__ __launch_bounds__(256) void k_scan_part(const int* __restrict__ deg,
                                                   int* __restrict__ bsum, int n) {
  int t = threadIdx.x;
  int idx = blockIdx.x * 256 + t;
  int v = (idx < n) ? deg[idx] : 0;
  int lane = t & 63, w = t >> 6;
  int x = v;
#pragma unroll
  for (int off = 1; off < 64; off <<= 1) {
    int y = __shfl_up(x, off);
    if (lane >= off) x += y;
  }
  __shared__ int ws[4];
  if (lane == 63) ws[w] = x;
  __syncthreads();
  if (t == 0) bsum[blockIdx.x] = ws[0] + ws[1] + ws[2] + ws[3];
}

__global__ __launch_bounds__(64) void k_scan_mid(const int* __restrict__ bsum,
                                                 int* __restrict__ boff, int nb) {
  int lane = threadIdx.x;
  int carry = 0;
  for (int base = 0; base < nb; base += 64) {
    int i = base + lane;
    int v = (i < nb) ? bsum[i] : 0;
    int x = v;
#pragma unroll
    for (int off = 1; off < 64; off <<= 1) {
      int y = __shfl_up(x, off);
      if (lane >= off) x += y;
    }
    if (i < nb) boff[i] = carry + x - v;
    carry += __shfl(x, 63);
  }
}

__global__ __launch_bounds__(256) void k_scan_apply(const int* __restrict__ deg,
                                                    const int* __restrict__ boff,
                                                    int* __restrict__ row_ptr,
                                                    int* __restrict__ cursor, int n, int e) {
  int t = threadIdx.x;
  int idx = blockIdx.x * 256 + t;
  int v = (idx < n) ? deg[idx] : 0;
  int lane = t & 63, w = t >> 6;
  int x = v;
#pragma unroll
  for (int off = 1; off < 64; off <<= 1) {
    int y = __shfl_up(x, off);
    if (lane >= off) x += y;
  }
  __shared__ int ws[4];
  if (lane == 63) ws[w] = x;
  __syncthreads();
  int wpre = 0;
  for (int i = 0; i < w; ++i) wpre += ws[i];
  if (idx < n) {
    row_ptr[idx] = boff[blockIdx.x] + wpre + x - v;
    cursor[idx] = 0;
  }
  if (idx == 0) row_ptr[n] = e;
}

__global__ void k_scatter(const int* __restrict__ src, const int* __restrict__ dst,
                          const int* __restrict__ row_ptr, int* cursor,
                          int* __restrict__ colbuf, int e) {
  int i = blockIdx.x * blockDim.x + threadIdx.x;
  if (i >= e) return;
  int d = dst[i];
  int p = atomicAdd(&cursor[d], 1);
  colbuf[row_ptr[d] + p] = src[i];
}

// ---------- fp16 MFMA GEMM (128x64 tile) for in/O projections: mode 0 plain, 1 ELU ----------
__global__ __launch_bounds__(256) void k_gemm_f16(
    const _Float16* __restrict__ A1, int K1,
    const _Float16* __restrict__ A2, int K2,
    const _Float16* __restrict__ Bt,
    const float* __restrict__ bias,
    _Float16* __restrict__ C,
    int M, int Ncols, int Ktot, int mode) {
  __shared__ half8 smem8[2 * 768];
  char* smem = (char*)smem8;
  const int tid = threadIdx.x;
  const int lane = tid & 63, wave = tid >> 6;
  const int wm = wave >> 1, wn = wave & 1;
  const int row0 = blockIdx.y * 128;
  const int col0 = blockIdx.x * 64;

  auto stage = [&](int buf, int k0) {
    char* sA = smem + buf * 12288;
    char* sB = sA + 8192;
#pragma unroll
    for (int i = 0; i < 2; ++i) {
      int kg = i * 2 + (wave >> 1);
      int row = (wave & 1) * 64 + lane;
      int grow = row0 + row; if (grow > M - 1) grow = M - 1;
      int k = k0 + kg * 8;
      const _Float16* src = (k < K1) ? (A1 + (size_t)grow * K1 + k)
                                     : (A2 + (size_t)grow * K2 + (k - K1));
      load16_to_lds(src, sA + (i * 256 + wave * 64) * 16);
    }
    {
      const _Float16* src = Bt + (size_t)(col0 + lane) * Ktot + k0 + wave * 8;
      load16_to_lds(src, sB + wave * 64 * 16);
    }
  };

  f32x4 acc[4][2];
#pragma unroll
  for (int mf = 0; mf < 4; ++mf)
#pragma unroll
    for (int nf = 0; nf < 2; ++nf) acc[mf][nf] = f32x4{0.f, 0.f, 0.f, 0.f};

  const int nsteps = Ktot >> 5;
  int cur = 0;
  stage(0, 0);
  __syncthreads();
  for (int st = 0; st < nsteps; ++st) {
    if (st + 1 < nsteps) stage(cur ^ 1, (st + 1) * 32);
    char* sA = smem + cur * 12288;
    char* sB = sA + 8192;
    half8 af[4], bf[2];
#pragma unroll
    for (int mf = 0; mf < 4; ++mf) {
      int slot = (lane >> 4) * 128 + wm * 64 + mf * 16 + (lane & 15);
      af[mf] = *(const half8*)(sA + slot * 16);
    }
#pragma unroll
    for (int nf = 0; nf < 2; ++nf) {
      int slot = (lane >> 4) * 64 + wn * 32 + nf * 16 + (lane & 15);
      bf[nf] = *(const half8*)(sB + slot * 16);
    }
#pragma unroll
    for (int mf = 0; mf < 4; ++mf)
#pragma unroll
      for (int nf = 0; nf < 2; ++nf)
        acc[mf][nf] = __builtin_amdgcn_mfma_f32_16x16x32_f16(af[mf], bf[nf], acc[mf][nf], 0, 0, 0);
    __syncthreads();
    cur ^= 1;
  }

  const int rbase = row0 + wm * 64 + (lane >> 4) * 4;
  const int cbase = col0 + wn * 32 + (lane & 15);
#pragma unroll
  for (int nf = 0; nf < 2; ++nf) {
    int col = cbase + nf * 16;
    float bv = bias[col];
#pragma unroll
    for (int mf = 0; mf < 4; ++mf) {
#pragma unroll
      for (int r = 0; r < 4; ++r) {
        int row = rbase + mf * 16 + r;
        if (row < M) {
          float v = acc[mf][nf][r] + bv;
          if (mode == 1) v = (v > 0.f) ? v : expm1f(v);
          C[(size_t)row * Ncols + col] = (_Float16)v;
        }
      }
    }
  }
}

// ---------- QKV GEMM: 128x32 tiles, XCD-PINNED (writes land on consumer's XCD L2) ----------
// 1-D grid of 24*R blocks (R = row tiles). xcd = bid&7, idx = bid>>3.
// idx < 2R : KV tile  (rowt = idx>>1, colt = 8 + xcd + 8*(idx&1))  -> head xcd K (colt<16) or V
// idx >= 2R: Q tile   (rowt = idx-2R, colt = xcd)
// attn head h runs on XCD h (blockIdx&7) and reads Q tile h + K/V head h -> all local L2.
__global__ __launch_bounds__(256) void k_gemm_qkv32(
    const _Float16* __restrict__ A1, int K1,
    const _Float16* __restrict__ A2, int K2,
    const _Float16* __restrict__ Bt,
    const float* __restrict__ bias,
    _Float16* __restrict__ Qb,
    _Float16* __restrict__ KV,
    int M, int Ktot, int R) {
  __shared__ half8 smem8[2 * 640];  // 2 x (8KB A + 2KB B) = 20KB
  char* smem = (char*)smem8;
  int b = blockIdx.x;
  int xcd = b & 7;
  int idx = b >> 3;
  int rowt, colt;
  if (idx < 2 * R) { rowt = idx >> 1; colt = 8 + xcd + 8 * (idx & 1); }
  else             { rowt = idx - 2 * R; colt = xcd; }
  const int row0 = rowt * 128;
  const int col0 = colt * 32;
  const int tid = threadIdx.x;
  const int lane = tid & 63, wave = tid >> 6;

  auto stage = [&](int buf, int k0) {
    char* sA = smem + buf * 10240;
    char* sB = sA + 8192;
#pragma unroll
    for (int i = 0; i < 2; ++i) {
      int kg = i * 2 + (wave >> 1);
      int row = (wave & 1) * 64 + lane;
      int grow = row0 + row; if (grow > M - 1) grow = M - 1;
      int k = k0 + kg * 8;
      const _Float16* src = (k < K1) ? (A1 + (size_t)grow * K1 + k)
                                     : (A2 + (size_t)grow * K2 + (k - K1));
      load16_to_lds(src, sA + (i * 256 + wave * 64) * 16);
    }
    if (lane < 32) {
      const _Float16* src = Bt + (size_t)(col0 + lane) * Ktot + k0 + wave * 8;
      load16_to_lds(src, sB + (wave * 32 + lane) * 16);
    }
  };

  f32x4 acc[2][2];
#pragma unroll
  for (int mf = 0; mf < 2; ++mf)
#pragma unroll
    for (int nf = 0; nf < 2; ++nf) acc[mf][nf] = f32x4{0.f, 0.f, 0.f, 0.f};

  const int nsteps = Ktot >> 5;
  int cur = 0;
  stage(0, 0);
  __syncthreads();
  for (int st = 0; st < nsteps; ++st) {
    if (st + 1 < nsteps) stage(cur ^ 1, (st + 1) * 32);
    char* sA = smem + cur * 10240;
    char* sB = sA + 8192;
    half8 af[2], bf[2];
#pragma unroll
    for (int mf = 0; mf < 2; ++mf) {
      int slot = (lane >> 4) * 128 + wave * 32 + mf * 16 + (lane & 15);
      af[mf] = *(const half8*)(sA + slot * 16);
    }
#pragma unroll
    for (int nf = 0; nf < 2; ++nf) {
      int slot = (lane >> 4) * 32 + nf * 16 + (lane & 15);
      bf[nf] = *(const half8*)(sB + slot * 16);
    }
#pragma unroll
    for (int mf = 0; mf < 2; ++mf)
#pragma unroll
      for (int nf = 0; nf < 2; ++nf)
        acc[mf][nf] = __builtin_amdgcn_mfma_f32_16x16x32_f16(af[mf], bf[nf], acc[mf][nf], 0, 0, 0);
    __syncthreads();
    cur ^= 1;
  }

  const int rbase = row0 + wave * 32 + (lane >> 4) * 4;
  const int lcol = lane & 15;
#pragma unroll
  for (int nf = 0; nf < 2; ++nf) {
    int cg = col0 + nf * 16 + lcol;    // global col in [0,768)
    float bv = bias[cg];
    int dim = nf * 16 + lcol + (col0 & 31);  // col0 is 32-aligned -> (col0&31)==0; dim = nf*16+lcol
#pragma unroll
    for (int mf = 0; mf < 2; ++mf) {
#pragma unroll
      for (int r = 0; r < 4; ++r) {
        int row = rbase + mf * 16 + r;
        if (row < M) {
          float v = acc[mf][nf][r] + bv;
          if (colt < 8) {
            Qb[(size_t)row * HID + cg] = (_Float16)v;
          } else {
            int isV = colt >= 16;
            int hh = colt - (isV ? 16 : 8);
            KV[((size_t)hh * M + row) * 64 + isV * 32 + dim] = (_Float16)v;
          }
        }
      }
    }
  }
}

// ---------- attention: head-split (L2-resident), fp16 K/V, 4 threads/node ----------
__global__ __launch_bounds__(256) void k_attn(const _Float16* __restrict__ Qb,
                                              const _Float16* __restrict__ KV,
                                              const int* __restrict__ row_ptr,
                                              const int* __restrict__ colbuf,
                                              _Float16* __restrict__ out, int n) {
  int h = blockIdx.x & 7;
  int node = (blockIdx.x >> 3) * 64 + (threadIdx.x >> 2);
  if (node >= n) return;
  int j = threadIdx.x & 3;   // dims j*8 .. j*8+7
  const float scale = 0.17677669529663687f;  // 1/sqrt(32)
  const _Float16* KVh = KV + ((size_t)h * n) * 64;

  half8 qh = *(const half8*)(Qb + (size_t)node * HID + h * 32 + j * 8);
  half8 qs;
#pragma unroll
  for (int q = 0; q < 8; ++q) qs[q] = (_Float16)((float)qh[q] * scale);

  int beg = row_ptr[node], end = row_ptr[node + 1];
  float m = -INFINITY, s = 0.f;
  float a[8] = {0.f, 0.f, 0.f, 0.f, 0.f, 0.f, 0.f, 0.f};

  for (int i = beg; i < end; i += 4) {
    half8 kk[4], vv[4];
#pragma unroll
    for (int t = 0; t < 4; ++t) {
      int ii = i + t; if (ii > end - 1) ii = end - 1;
      int sn = colbuf[ii];
      const _Float16* b = KVh + ((size_t)sn) * 64 + j * 8;
      kk[t] = *(const half8*)(b);
      vv[t] = *(const half8*)(b + 32);
    }
    float p[4];
#pragma unroll
    for (int t = 0; t < 4; ++t) p[t] = dot8h(qs, kk[t], 0.f);
#pragma unroll
    for (int t = 0; t < 4; ++t) {
      p[t] += __shfl_xor(p[t], 1);
      p[t] += __shfl_xor(p[t], 2);
      if (i + t >= end) p[t] = -INFINITY;  // tail mask (t=0 always real)
    }
#pragma unroll
    for (int t = 0; t < 4; ++t) {
      float sc_ = p[t];
      if (sc_ <= m) {
        float e2 = __expf(sc_ - m);
        s += e2;
#pragma unroll
        for (int q = 0; q < 8; ++q) a[q] = fmaf(e2, (float)vv[t][q], a[q]);
      } else {
        float f = __expf(m - sc_);  // m=-inf on first real edge -> f=0
        s = s * f + 1.f;
#pragma unroll
        for (int q = 0; q < 8; ++q) a[q] = fmaf(a[q], f, (float)vv[t][q]);
        m = sc_;
      }
    }
  }

  float inv = (s > 0.f) ? (1.f / s) : 0.f;
  half8 o;
#pragma unroll
  for (int q = 0; q < 8; ++q) o[q] = (_Float16)(a[q] * inv);
  *(half8*)(out + (size_t)node * HID + h * 32 + j * 8) = o;
}

// ---------- pooling + classifier ----------
__global__ __launch_bounds__(256) void k_pool_partial(const _Float16* __restrict__ h,
                                                      float* __restrict__ partial, int n) {
  int b = blockIdx.x, t = threadIdx.x;
  float s = 0.f;
  for (int r = b; r < n; r += 256) s += (float)h[(size_t)r * HID + t];
  partial[b * HID + t] = s;
}

__global__ __launch_bounds__(256) void k_final(const float* __restrict__ partial,
                                               const float* __restrict__ c1W,
                                               const float* __restrict__ c1b,
                                               const float* __restrict__ c2W,
                                               const float* __restrict__ c2b,
                                               float* __restrict__ out, int n) {
  __shared__ float gl[HID];
  __shared__ float r1[C1DIM];
  int t = threadIdx.x;
  float s = 0.f;
  for (int b = 0; b < 256; b++) s += partial[b * HID + t];
  gl[t] = s / (float)n;
  __syncthreads();
  if (t < C1DIM) {
    float a = c1b[t];
    for (int k = 0; k < HID; k++) a += gl[k] * c1W[k * C1DIM + t];
    r1[t] = fmaxf(a, 0.f);
  }
  __syncthreads();
  if (t < OUTDIM) {
    float a = c2b[t];
    for (int k = 0; k < C1DIM; k++) a += r1[k] * c2W[k * OUTDIM + t];
    out[t] = a;
  }
}

// ---------- host launcher ----------
extern "C" void kernel_launch(void* const* d_in, const int* in_sizes, int n_in,
                              void* d_out, int out_size, void* d_ws, size_t ws_size,
                              hipStream_t stream) {
  const float* x    = (const float*)d_in[0];
  const float* ts   = (const float*)d_in[1];
  const int*   ei   = (const int*)d_in[2];
  const float* freq = (const float*)d_in[4];
  const float* inW  = (const float*)d_in[5];
  const float* inb  = (const float*)d_in[6];
  const float* qW   = (const float*)d_in[7];
  const float* qb   = (const float*)d_in[8];
  const float* kW   = (const float*)d_in[9];
  const float* kb   = (const float*)d_in[10];
  const float* vW   = (const float*)d_in[11];
  const float* vb   = (const float*)d_in[12];
  const float* oW   = (const float*)d_in[13];
  const float* ob   = (const float*)d_in[14];
  const float* c1W  = (const float*)d_in[15];
  const float* c1b  = (const float*)d_in[16];
  const float* c2W  = (const float*)d_in[17];
  const float* c2b  = (const float*)d_in[18];

  int n = in_sizes[1];
  int e = in_sizes[2] / 2;
  const int* src = ei;
  const int* dst = ei + e;
  int nb = (n + 255) / 256;
  int R = (n + 127) / 128;

  char* w = (char*)d_ws;
  size_t off = 0;
  auto alloc = [&](size_t bytes) -> char* {
    char* p = w + off;
    off = (off + bytes + 255) & ~(size_t)255;
    return p;
  };
  _Float16* tfh     = (_Float16*)alloc((size_t)n * TD * 2);
  _Float16* xh      = (_Float16*)alloc((size_t)n * 32 * 2);
  _Float16* h       = (_Float16*)alloc((size_t)n * HID * 2);
  _Float16* Qbuf    = (_Float16*)alloc((size_t)n * HID * 2);
  _Float16* KV      = (_Float16*)alloc((size_t)n * 512 * 2);
  _Float16* ao      = (_Float16*)alloc((size_t)n * HID * 2);
  _Float16* qkvWt   = (_Float16*)alloc((size_t)NL * QKVW * (HID + TD) * 2);
  float*    qkvb    = (float*)alloc((size_t)NL * QKVW * 4);
  _Float16* oWt     = (_Float16*)alloc((size_t)NL * HID * HID * 2);
  _Float16* WcT     = (_Float16*)alloc((size_t)QKVW * 64 * 2);
  float*    bc      = (float*)alloc((size_t)QKVW * 4);
  int*      deg     = (int*)alloc((size_t)n * 4);
  int*      cursor  = (int*)alloc((size_t)n * 4);
  int*      row_ptr = (int*)alloc((size_t)(n + 1) * 4);
  int*      colbuf  = (int*)alloc((size_t)e * 4);
  int*      bsum    = (int*)alloc((size_t)nb * 4);
  int*      boff    = (int*)alloc((size_t)nb * 4);
  float*    partial = (float*)alloc((size_t)256 * HID * 4);
  float*    mmf     = (float*)alloc(256);

  int b256 = 256;
  hipLaunchKernelGGL(k_tsmm, dim3(1), dim3(1024), 0, stream, ts, mmf, deg, n);
  hipLaunchKernelGGL(k_enc, dim3((n * 64 + 255) / 256), dim3(b256), 0, stream,
                     ts, freq, mmf, x, tfh, xh, n);
  hipLaunchKernelGGL(k_prep2, dim3(NB_QKV + NB_O + NB_B), dim3(b256), 0, stream,
                     qW, kW, vW, oW, qb, kb, vb, qkvWt, qkvb, oWt);
  hipLaunchKernelGGL(k_fold, dim3((65 * QKVW + 255) / 256), dim3(b256), 0, stream,
                     inW, inb, qW, kW, vW, qb, kb, vb, WcT, bc);
  hipLaunchKernelGGL(k_count, dim3((e + 255) / 256), dim3(b256), 0, stream, dst, deg, e);
  hipLaunchKernelGGL(k_scan_part, dim3(nb), dim3(b256), 0, stream, deg, bsum, n);
  hipLaunchKernelGGL(k_scan_mid, dim3(1), dim3(64), 0, stream, bsum, boff, nb);
  hipLaunchKernelGGL(k_scan_apply, dim3(nb), dim3(b256), 0, stream, deg, boff, row_ptr, cursor, n, e);
  hipLaunchKernelGGL(k_scatter, dim3((e + 255) / 256), dim3(b256), 0, stream, src, dst, row_ptr, cursor, colbuf, e);

  dim3 ggrid_h(HID / 64, (n + 127) / 128);
  int nchunks = (n + 63) / 64;
  for (int l = 0; l < NL; ++l) {
    const float*    qkvbl = qkvb + (size_t)l * QKVW;
    const _Float16* oWtl  = oWt + (size_t)l * HID * HID;
    if (l == 0) {
      hipLaunchKernelGGL(k_gemm_qkv32, dim3(24 * R), dim3(b256), 0, stream,
                         xh, 32, tfh, 32, WcT, bc, Qbuf, KV, n, 64, R);
    } else {
      const _Float16* qkvWtl = qkvWt + (size_t)l * QKVW * (HID + TD);
      hipLaunchKernelGGL(k_gemm_qkv32, dim3(24 * R), dim3(b256), 0, stream,
                         h, HID, tfh, TD, qkvWtl, qkvbl, Qbuf, KV, n, HID + TD, R);
    }
    hipLaunchKernelGGL(k_attn, dim3(nchunks * 8), dim3(b256), 0, stream,
                       Qbuf, KV, row_ptr, colbuf, ao, n);
    hipLaunchKernelGGL(k_gemm_f16, ggrid_h, dim3(b256), 0, stream,
                       ao, HID, ao, HID, oWtl, ob + l * HID, h, n, HID, HID, 1);
  }

  hipLaunchKernelGGL(k_pool_partial, dim3(256), dim3(b256), 0, stream, h, partial, n);
  hipLaunchKernelGGL(k_final, dim3(1), dim3(b256), 0, stream, partial, c1W, c1b, c2W, c2b, (float*)d_out, n);
}

// Round 16
// 481.961 us; speedup vs baseline: 1.0182x; 1.0182x over previous
//
#include <hip/hip_runtime.h>
#include <math.h>

#define HID 256
#define TD 32
#define NL 3
#define C1DIM 128
#define OUTDIM 2
#define QKVW 768

using half8  = __attribute__((ext_vector_type(8))) _Float16;
using half2v = __attribute__((ext_vector_type(2))) _Float16;
using f32x4  = __attribute__((ext_vector_type(4))) float;

typedef __attribute__((address_space(1))) void gbl_void_t;
typedef __attribute__((address_space(3))) void lds_void_t;

__device__ __forceinline__ void load16_to_lds(const void* g, void* l) {
  __builtin_amdgcn_global_load_lds((const gbl_void_t*)g, (lds_void_t*)l, 16, 0, 0);
}

__device__ __forceinline__ float dot8h(half8 a, half8 b, float acc) {
#if __has_builtin(__builtin_amdgcn_fdot2)
  union { half8 v; half2v h2[4]; } ua, ub;
  ua.v = a; ub.v = b;
#pragma unroll
  for (int j = 0; j < 4; ++j) acc = __builtin_amdgcn_fdot2(ua.h2[j], ub.h2[j], acc, false);
  return acc;
#else
#pragma unroll
  for (int j = 0; j < 8; ++j) acc += (float)a[j] * (float)b[j];
  return acc;
#endif
}

// permuted fused col -> original fused col.
// permuted layout: [Q 0..255 | head0: K(32) V(32) | head1: K V | ... | head7]
__device__ __forceinline__ int ipermc(int c) {
  if (c < 256) return c;
  int t = c - 256, h = t >> 6, w = t & 63, isV = w >> 5, d = w & 31;
  return 256 + isV * 256 + h * 32 + d;
}

// ---------- setup: ts min/max (single block) + zero deg ----------
__global__ __launch_bounds__(1024) void k_tsmm(const float* __restrict__ ts,
                                               float* __restrict__ mmf,
                                               int* __restrict__ deg, int n) {
  int t = threadIdx.x;
  float lmin = INFINITY, lmax = -INFINITY;
  for (int i = t; i < n; i += 1024) {
    float v = ts[i];
    lmin = fminf(lmin, v);
    lmax = fmaxf(lmax, v);
    deg[i] = 0;
  }
#pragma unroll
  for (int off = 32; off >= 1; off >>= 1) {
    lmin = fminf(lmin, __shfl_xor(lmin, off));
    lmax = fmaxf(lmax, __shfl_xor(lmax, off));
  }
  __shared__ float wmin[16], wmax[16];
  int lane = t & 63, w = t >> 6;
  if (lane == 0) { wmin[w] = lmin; wmax[w] = lmax; }
  __syncthreads();
  if (t == 0) {
    float a = INFINITY, b = -INFINITY;
    for (int i = 0; i < 16; ++i) { a = fminf(a, wmin[i]); b = fmaxf(b, wmax[i]); }
    mmf[0] = a; mmf[1] = b;
  }
}

// ---------- merged time encoding + x conversion ----------
__global__ void k_enc(const float* __restrict__ ts, const float* __restrict__ freq,
                      const float* __restrict__ mmf, const float* __restrict__ x,
                      _Float16* __restrict__ tfh, _Float16* __restrict__ xh, int n) {
  int idx = blockIdx.x * blockDim.x + threadIdx.x;
  int nt = n * TD;
  if (idx < nt) {
    int node = idx >> 5, j = idx & 31;
    float t = (ts[node] - mmf[0]) / (mmf[1] - mmf[0] + 1e-8f);
    float w = t * freq[j & 15];
    tfh[idx] = (_Float16)((j < 16) ? cosf(w) : sinf(w));
  } else if (idx < nt + n * 32) {
    int i2 = idx - nt;
    xh[i2] = (_Float16)x[i2];
  }
}

// ---------- LDS-tiled weight prep (permuted QKV cols) ----------
#define NB_QKV (NL * 9 * 12)   // k-tiles 288/32 x n-tiles 768/64
#define NB_O   (NL * 8 * 4)    // 256/32 x 256/64
#define NB_B   9               // NL*768 / 256

__global__ __launch_bounds__(256) void k_prep2(
    const float* __restrict__ qW, const float* __restrict__ kW,
    const float* __restrict__ vW, const float* __restrict__ oW,
    const float* __restrict__ qb, const float* __restrict__ kb,
    const float* __restrict__ vb,
    _Float16* __restrict__ qkvWt, float* __restrict__ qkvb,
    _Float16* __restrict__ oWt) {
  __shared__ _Float16 lds[32][65];
  int bid = blockIdx.x;
  int t = threadIdx.x;
  const int KQ = HID + TD;  // 288

  if (bid < NB_QKV) {
    int l = bid / 108;
    int rem = bid - l * 108;
    int kt = rem / 12, ntile = rem - kt * 12;
    int k0 = kt * 32, n0 = ntile * 64;
#pragma unroll
    for (int it = 0; it < 8; ++it) {
      int i = it * 256 + t;
      int kk = i >> 6, nn = i & 63;
      int k = k0 + kk;
      int orig = ipermc(n0 + nn);
      float v;
      if (orig < 256)      v = qW[(size_t)l * KQ * HID + (size_t)k * HID + orig];
      else if (orig < 512) v = kW[(size_t)l * KQ * HID + (size_t)k * HID + (orig - 256)];
      else                 v = (k < HID) ? vW[(size_t)l * HID * HID + (size_t)k * HID + (orig - 512)] : 0.f;
      lds[kk][nn] = (_Float16)v;
    }
    __syncthreads();
    {
      int nn = t >> 2, kq = (t & 3) * 8;
      _Float16* dst = qkvWt + (size_t)l * QKVW * KQ + (size_t)(n0 + nn) * KQ + k0 + kq;
      half8 v;
#pragma unroll
      for (int j = 0; j < 8; ++j) v[j] = lds[kq + j][nn];
      *(half8*)dst = v;
    }
    return;
  }
  bid -= NB_QKV;

  if (bid < NB_O) {
    int l = bid / 32;
    int rem = bid - l * 32;
    int kt = rem / 4, ntile = rem - kt * 4;
    int k0 = kt * 32, n0 = ntile * 64;
#pragma unroll
    for (int it = 0; it < 8; ++it) {
      int i = it * 256 + t;
      int kk = i >> 6, nn = i & 63;
      lds[kk][nn] = (_Float16)oW[(size_t)l * HID * HID + (size_t)(k0 + kk) * HID + n0 + nn];
    }
    __syncthreads();
    {
      int nn = t >> 2, kq = (t & 3) * 8;
      _Float16* dst = oWt + (size_t)l * HID * HID + (size_t)(n0 + nn) * HID + k0 + kq;
      half8 v;
#pragma unroll
      for (int j = 0; j < 8; ++j) v[j] = lds[kq + j][nn];
      *(half8*)dst = v;
    }
    return;
  }
  bid -= NB_O;

  {
    int idx = bid * 256 + t;
    if (idx < NL * QKVW) {
      int l = idx / QKVW;
      int j = idx - l * QKVW;
      int orig = ipermc(j);
      float v;
      if (orig < 256)      v = qb[l * HID + orig];
      else if (orig < 512) v = kb[l * HID + (orig - 256)];
      else                 v = vb[l * HID + (orig - 512)];
      qkvb[idx] = v;
    }
  }
}

// ---------- layer-0 fold (permuted): WcT[768][64], bc[768] ----------
__global__ __launch_bounds__(256) void k_fold(const float* __restrict__ inW,
                                              const float* __restrict__ inb,
                                              const float* __restrict__ qW,
                                              const float* __restrict__ kW,
                                              const float* __restrict__ vW,
                                              const float* __restrict__ qb,
                                              const float* __restrict__ kb,
                                              const float* __restrict__ vb,
                                              _Float16* __restrict__ WcT,
                                              float* __restrict__ bc) {
  int idx = blockIdx.x * 256 + threadIdx.x;
  if (idx >= 65 * QKVW) return;
  int j = idx / QKVW;
  int nrowP = idx - j * QKVW;
  int orig = ipermc(nrowP);
  auto W0 = [&](int c, int nr) -> float {
    if (nr < 256)      return qW[(size_t)c * HID + nr];
    else if (nr < 512) return kW[(size_t)c * HID + (nr - 256)];
    else               return vW[(size_t)c * HID + (nr - 512)];
  };
  if (j < 32) {
    float acc = 0.f;
    for (int c = 0; c < 256; ++c) acc += inW[j * HID + c] * W0(c, orig);
    WcT[(size_t)nrowP * 64 + j] = (_Float16)acc;
  } else if (j < 64) {
    int r = 256 + (j - 32);
    float v = 0.f;
    if (orig < 256)      v = qW[(size_t)r * HID + orig];
    else if (orig < 512) v = kW[(size_t)r * HID + (orig - 256)];
    WcT[(size_t)nrowP * 64 + j] = (_Float16)v;
  } else {
    float acc;
    if (orig < 256)      acc = qb[orig];
    else if (orig < 512) acc = kb[orig - 256];
    else                 acc = vb[orig - 512];
    for (int c = 0; c < 256; ++c) acc += inb[c] * W0(c, orig);
    bc[nrowP] = acc;
  }
}

__global__ void k_count(const int* __restrict__ dst, int* deg, int e) {
  int i = blockIdx.x * blockDim.x + threadIdx.x;
  if (i < e) atomicAdd(&deg[dst[i]], 1);
}

// ---------- 3-kernel scan ----------
__global__ __launch_bounds__(256) void k_scan_part(const int* __restrict__ deg,
                                                   int* __restrict__ bsum, int n) {
  int t = threadIdx.x;
  int idx = blockIdx.x * 256 + t;
  int v = (idx < n) ? deg[idx] : 0;
  int lane = t & 63, w = t >> 6;
  int x = v;
#pragma unroll
  for (int off = 1; off < 64; off <<= 1) {
    int y = __shfl_up(x, off);
    if (lane >= off) x += y;
  }
  __shared__ int ws[4];
  if (lane == 63) ws[w] = x;
  __syncthreads();
  if (t == 0) bsum[blockIdx.x] = ws[0] + ws[1] + ws[2] + ws[3];
}

__global__ __launch_bounds__(64) void k_scan_mid(const int* __restrict__ bsum,
                                                 int* __restrict__ boff, int nb) {
  int lane = threadIdx.x;
  int carry = 0;
  for (int base = 0; base < nb; base += 64) {
    int i = base + lane;
    int v = (i < nb) ? bsum[i] : 0;
    int x = v;
#pragma unroll
    for (int off = 1; off < 64; off <<= 1) {
      int y = __shfl_up(x, off);
      if (lane >= off) x += y;
    }
    if (i < nb) boff[i] = carry + x - v;
    carry += __shfl(x, 63);
  }
}

__global__ __launch_bounds__(256) void k_scan_apply(const int* __restrict__ deg,
                                                    const int* __restrict__ boff,
                                                    int* __restrict__ row_ptr,
                                                    int* __restrict__ cursor, int n, int e) {
  int t = threadIdx.x;
  int idx = blockIdx.x * 256 + t;
  int v = (idx < n) ? deg[idx] : 0;
  int lane = t & 63, w = t >> 6;
  int x = v;
#pragma unroll
  for (int off = 1; off < 64; off <<= 1) {
    int y = __shfl_up(x, off);
    if (lane >= off) x += y;
  }
  __shared__ int ws[4];
  if (lane == 63) ws[w] = x;
  __syncthreads();
  int wpre = 0;
  for (int i = 0; i < w; ++i) wpre += ws[i];
  if (idx < n) {
    row_ptr[idx] = boff[blockIdx.x] + wpre + x - v;
    cursor[idx] = 0;
  }
  if (idx == 0) row_ptr[n] = e;
}

__global__ void k_scatter(const int* __restrict__ src, const int* __restrict__ dst,
                          const int* __restrict__ row_ptr, int* cursor,
                          int* __restrict__ colbuf, int e) {
  int i = blockIdx.x * blockDim.x + threadIdx.x;
  if (i >= e) return;
  int d = dst[i];
  int p = atomicAdd(&cursor[d], 1);
  colbuf[row_ptr[d] + p] = src[i];
}

// ---------- fp16 MFMA GEMM (128x64 tile) for O projection: mode 0 plain, 1 ELU ----------
__global__ __launch_bounds__(256) void k_gemm_f16(
    const _Float16* __restrict__ A1, int K1,
    const _Float16* __restrict__ A2, int K2,
    const _Float16* __restrict__ Bt,
    const float* __restrict__ bias,
    _Float16* __restrict__ C,
    int M, int Ncols, int Ktot, int mode) {
  __shared__ half8 smem8[2 * 768];
  char* smem = (char*)smem8;
  const int tid = threadIdx.x;
  const int lane = tid & 63, wave = tid >> 6;
  const int wm = wave >> 1, wn = wave & 1;
  const int row0 = blockIdx.y * 128;
  const int col0 = blockIdx.x * 64;

  auto stage = [&](int buf, int k0) {
    char* sA = smem + buf * 12288;
    char* sB = sA + 8192;
#pragma unroll
    for (int i = 0; i < 2; ++i) {
      int kg = i * 2 + (wave >> 1);
      int row = (wave & 1) * 64 + lane;
      int grow = row0 + row; if (grow > M - 1) grow = M - 1;
      int k = k0 + kg * 8;
      const _Float16* src = (k < K1) ? (A1 + (size_t)grow * K1 + k)
                                     : (A2 + (size_t)grow * K2 + (k - K1));
      load16_to_lds(src, sA + (i * 256 + wave * 64) * 16);
    }
    {
      const _Float16* src = Bt + (size_t)(col0 + lane) * Ktot + k0 + wave * 8;
      load16_to_lds(src, sB + wave * 64 * 16);
    }
  };

  f32x4 acc[4][2];
#pragma unroll
  for (int mf = 0; mf < 4; ++mf)
#pragma unroll
    for (int nf = 0; nf < 2; ++nf) acc[mf][nf] = f32x4{0.f, 0.f, 0.f, 0.f};

  const int nsteps = Ktot >> 5;
  int cur = 0;
  stage(0, 0);
  __syncthreads();
  for (int st = 0; st < nsteps; ++st) {
    if (st + 1 < nsteps) stage(cur ^ 1, (st + 1) * 32);
    char* sA = smem + cur * 12288;
    char* sB = sA + 8192;
    half8 af[4], bf[2];
#pragma unroll
    for (int mf = 0; mf < 4; ++mf) {
      int slot = (lane >> 4) * 128 + wm * 64 + mf * 16 + (lane & 15);
      af[mf] = *(const half8*)(sA + slot * 16);
    }
#pragma unroll
    for (int nf = 0; nf < 2; ++nf) {
      int slot = (lane >> 4) * 64 + wn * 32 + nf * 16 + (lane & 15);
      bf[nf] = *(const half8*)(sB + slot * 16);
    }
#pragma unroll
    for (int mf = 0; mf < 4; ++mf)
#pragma unroll
      for (int nf = 0; nf < 2; ++nf)
        acc[mf][nf] = __builtin_amdgcn_mfma_f32_16x16x32_f16(af[mf], bf[nf], acc[mf][nf], 0, 0, 0);
    __syncthreads();
    cur ^= 1;
  }

  const int rbase = row0 + wm * 64 + (lane >> 4) * 4;
  const int cbase = col0 + wn * 32 + (lane & 15);
#pragma unroll
  for (int nf = 0; nf < 2; ++nf) {
    int col = cbase + nf * 16;
    float bv = bias[col];
#pragma unroll
    for (int mf = 0; mf < 4; ++mf) {
#pragma unroll
      for (int r = 0; r < 4; ++r) {
        int row = rbase + mf * 16 + r;
        if (row < M) {
          float v = acc[mf][nf][r] + bv;
          if (mode == 1) v = (v > 0.f) ? v : expm1f(v);
          C[(size_t)row * Ncols + col] = (_Float16)v;
        }
      }
    }
  }
}

// ---------- QKV GEMM: 128x64 tiles, permuted cols, XCD-pinned KV tiles ----------
// 1-D grid of 8*(R + ceil(R/2)) blocks. xcd = bid&7, i = bid>>3.
// i < R  : KV tile of head xcd (ct = 4+xcd, rowt = i)  -> writes land on XCD xcd's L2
// i >= R : Q tile: j = (i-R)*8+xcd in [0,4R): ct = j&3, rowt = j>>2
__global__ __launch_bounds__(256) void k_gemm_qkvp(
    const _Float16* __restrict__ A1, int K1,
    const _Float16* __restrict__ A2, int K2,
    const _Float16* __restrict__ Bt,
    const float* __restrict__ bias,
    _Float16* __restrict__ Qb,
    _Float16* __restrict__ KV,
    int M, int Ktot, int R) {
  int xcd = blockIdx.x & 7;
  int i = blockIdx.x >> 3;
  int ct, rowt;
  if (i < R) { ct = 4 + xcd; rowt = i; }
  else {
    int j = (i - R) * 8 + xcd;
    if (j >= 4 * R) return;
    ct = j & 3; rowt = j >> 2;
  }
  __shared__ half8 smem8[2 * 768];
  char* smem = (char*)smem8;
  const int tid = threadIdx.x;
  const int lane = tid & 63, wave = tid >> 6;
  const int wm = wave >> 1, wn = wave & 1;
  const int row0 = rowt * 128;
  const int col0 = ct * 64;

  auto stage = [&](int buf, int k0) {
    char* sA = smem + buf * 12288;
    char* sB = sA + 8192;
#pragma unroll
    for (int ii = 0; ii < 2; ++ii) {
      int kg = ii * 2 + (wave >> 1);
      int row = (wave & 1) * 64 + lane;
      int grow = row0 + row; if (grow > M - 1) grow = M - 1;
      int k = k0 + kg * 8;
      const _Float16* src = (k < K1) ? (A1 + (size_t)grow * K1 + k)
                                     : (A2 + (size_t)grow * K2 + (k - K1));
      load16_to_lds(src, sA + (ii * 256 + wave * 64) * 16);
    }
    {
      const _Float16* src = Bt + (size_t)(col0 + lane) * Ktot + k0 + wave * 8;
      load16_to_lds(src, sB + wave * 64 * 16);
    }
  };

  f32x4 acc[4][2];
#pragma unroll
  for (int mf = 0; mf < 4; ++mf)
#pragma unroll
    for (int nf = 0; nf < 2; ++nf) acc[mf][nf] = f32x4{0.f, 0.f, 0.f, 0.f};

  const int nsteps = Ktot >> 5;
  int cur = 0;
  stage(0, 0);
  __syncthreads();
  for (int st = 0; st < nsteps; ++st) {
    if (st + 1 < nsteps) stage(cur ^ 1, (st + 1) * 32);
    char* sA = smem + cur * 12288;
    char* sB = sA + 8192;
    half8 af[4], bf[2];
#pragma unroll
    for (int mf = 0; mf < 4; ++mf) {
      int slot = (lane >> 4) * 128 + wm * 64 + mf * 16 + (lane & 15);
      af[mf] = *(const half8*)(sA + slot * 16);
    }
#pragma unroll
    for (int nf = 0; nf < 2; ++nf) {
      int slot = (lane >> 4) * 64 + wn * 32 + nf * 16 + (lane & 15);
      bf[nf] = *(const half8*)(sB + slot * 16);
    }
#pragma unroll
    for (int mf = 0; mf < 4; ++mf)
#pragma unroll
      for (int nf = 0; nf < 2; ++nf)
        acc[mf][nf] = __builtin_amdgcn_mfma_f32_16x16x32_f16(af[mf], bf[nf], acc[mf][nf], 0, 0, 0);
    __syncthreads();
    cur ^= 1;
  }

  const int rbase = row0 + wm * 64 + (lane >> 4) * 4;
  const int cbase = col0 + wn * 32 + (lane & 15);
#pragma unroll
  for (int nf = 0; nf < 2; ++nf) {
    int col = cbase + nf * 16;       // permuted fused col
    float bv = bias[col];
    int w = col - col0;              // within-tile [0,64)
    int isV = w >> 5, d = w & 31;
    int hh = ct - 4;
#pragma unroll
    for (int mf = 0; mf < 4; ++mf) {
#pragma unroll
      for (int r = 0; r < 4; ++r) {
        int row = rbase + mf * 16 + r;
        if (row < M) {
          float v = acc[mf][nf][r] + bv;
          if (ct < 4) Qb[(size_t)row * HID + col] = (_Float16)v;
          else        KV[((size_t)hh * M + row) * 64 + isV * 32 + d] = (_Float16)v;
        }
      }
    }
  }
}

// ---------- attention: head-split (head = blockIdx&7 = XCD), fp16 K/V, 4 threads/node ----------
__global__ __launch_bounds__(256) void k_attn(const _Float16* __restrict__ Qb,
                                              const _Float16* __restrict__ KV,
                                              const int* __restrict__ row_ptr,
                                              const int* __restrict__ colbuf,
                                              _Float16* __restrict__ out, int n) {
  int h = blockIdx.x & 7;
  int node = (blockIdx.x >> 3) * 64 + (threadIdx.x >> 2);
  if (node >= n) return;
  int j = threadIdx.x & 3;   // dims j*8 .. j*8+7
  const float scale = 0.17677669529663687f;  // 1/sqrt(32)
  const _Float16* KVh = KV + ((size_t)h * n) * 64;

  half8 qh = *(const half8*)(Qb + (size_t)node * HID + h * 32 + j * 8);
  half8 qs;
#pragma unroll
  for (int q = 0; q < 8; ++q) qs[q] = (_Float16)((float)qh[q] * scale);

  int beg = row_ptr[node], end = row_ptr[node + 1];
  float m = -INFINITY, s = 0.f;
  float a[8] = {0.f, 0.f, 0.f, 0.f, 0.f, 0.f, 0.f, 0.f};

  for (int i = beg; i < end; i += 4) {
    half8 kk[4], vv[4];
#pragma unroll
    for (int t = 0; t < 4; ++t) {
      int ii = i + t; if (ii > end - 1) ii = end - 1;
      int sn = colbuf[ii];
      const _Float16* b = KVh + ((size_t)sn) * 64 + j * 8;
      kk[t] = *(const half8*)(b);
      vv[t] = *(const half8*)(b + 32);
    }
    float p[4];
#pragma unroll
    for (int t = 0; t < 4; ++t) p[t] = dot8h(qs, kk[t], 0.f);
#pragma unroll
    for (int t = 0; t < 4; ++t) {
      p[t] += __shfl_xor(p[t], 1);
      p[t] += __shfl_xor(p[t], 2);
      if (i + t >= end) p[t] = -INFINITY;  // tail mask (t=0 always real)
    }
#pragma unroll
    for (int t = 0; t < 4; ++t) {
      float sc_ = p[t];
      if (sc_ <= m) {
        float e2 = __expf(sc_ - m);
        s += e2;
#pragma unroll
        for (int q = 0; q < 8; ++q) a[q] = fmaf(e2, (float)vv[t][q], a[q]);
      } else {
        float f = __expf(m - sc_);  // m=-inf on first real edge -> f=0
        s = s * f + 1.f;
#pragma unroll
        for (int q = 0; q < 8; ++q) a[q] = fmaf(a[q], f, (float)vv[t][q]);
        m = sc_;
      }
    }
  }

  float inv = (s > 0.f) ? (1.f / s) : 0.f;
  half8 o;
#pragma unroll
  for (int q = 0; q < 8; ++q) o[q] = (_Float16)(a[q] * inv);
  *(half8*)(out + (size_t)node * HID + h * 32 + j * 8) = o;
}

// ---------- pooling + classifier ----------
__global__ __launch_bounds__(256) void k_pool_partial(const _Float16* __restrict__ h,
                                                      float* __restrict__ partial, int n) {
  int b = blockIdx.x, t = threadIdx.x;
  float s = 0.f;
  for (int r = b; r < n; r += 256) s += (float)h[(size_t)r * HID + t];
  partial[b * HID + t] = s;
}

__global__ __launch_bounds__(256) void k_final(const float* __restrict__ partial,
                                               const float* __restrict__ c1W,
                                               const float* __restrict__ c1b,
                                               const float* __restrict__ c2W,
                                               const float* __restrict__ c2b,
                                               float* __restrict__ out, int n) {
  __shared__ float gl[HID];
  __shared__ float r1[C1DIM];
  int t = threadIdx.x;
  float s = 0.f;
  for (int b = 0; b < 256; b++) s += partial[b * HID + t];
  gl[t] = s / (float)n;
  __syncthreads();
  if (t < C1DIM) {
    float a = c1b[t];
    for (int k = 0; k < HID; k++) a += gl[k] * c1W[k * C1DIM + t];
    r1[t] = fmaxf(a, 0.f);
  }
  __syncthreads();
  if (t < OUTDIM) {
    float a = c2b[t];
    for (int k = 0; k < C1DIM; k++) a += r1[k] * c2W[k * OUTDIM + t];
    out[t] = a;
  }
}

// ---------- host launcher ----------
extern "C" void kernel_launch(void* const* d_in, const int* in_sizes, int n_in,
                              void* d_out, int out_size, void* d_ws, size_t ws_size,
                              hipStream_t stream) {
  const float* x    = (const float*)d_in[0];
  const float* ts   = (const float*)d_in[1];
  const int*   ei   = (const int*)d_in[2];
  const float* freq = (const float*)d_in[4];
  const float* inW  = (const float*)d_in[5];
  const float* inb  = (const float*)d_in[6];
  const float* qW   = (const float*)d_in[7];
  const float* qb   = (const float*)d_in[8];
  const float* kW   = (const float*)d_in[9];
  const float* kb   = (const float*)d_in[10];
  const float* vW   = (const float*)d_in[11];
  const float* vb   = (const float*)d_in[12];
  const float* oW   = (const float*)d_in[13];
  const float* ob   = (const float*)d_in[14];
  const float* c1W  = (const float*)d_in[15];
  const float* c1b  = (const float*)d_in[16];
  const float* c2W  = (const float*)d_in[17];
  const float* c2b  = (const float*)d_in[18];

  int n = in_sizes[1];
  int e = in_sizes[2] / 2;
  const int* src = ei;
  const int* dst = ei + e;
  int nb = (n + 255) / 256;
  int R = (n + 127) / 128;
  int qkv_grid = 8 * (R + (R + 1) / 2);

  char* w = (char*)d_ws;
  size_t off = 0;
  auto alloc = [&](size_t bytes) -> char* {
    char* p = w + off;
    off = (off + bytes + 255) & ~(size_t)255;
    return p;
  };
  _Float16* tfh     = (_Float16*)alloc((size_t)n * TD * 2);
  _Float16* xh      = (_Float16*)alloc((size_t)n * 32 * 2);
  _Float16* h       = (_Float16*)alloc((size_t)n * HID * 2);
  _Float16* Qbuf    = (_Float16*)alloc((size_t)n * HID * 2);
  _Float16* KV      = (_Float16*)alloc((size_t)n * 512 * 2);
  _Float16* ao      = (_Float16*)alloc((size_t)n * HID * 2);
  _Float16* qkvWt   = (_Float16*)alloc((size_t)NL * QKVW * (HID + TD) * 2);
  float*    qkvb    = (float*)alloc((size_t)NL * QKVW * 4);
  _Float16* oWt     = (_Float16*)alloc((size_t)NL * HID * HID * 2);
  _Float16* WcT     = (_Float16*)alloc((size_t)QKVW * 64 * 2);
  float*    bc      = (float*)alloc((size_t)QKVW * 4);
  int*      deg     = (int*)alloc((size_t)n * 4);
  int*      cursor  = (int*)alloc((size_t)n * 4);
  int*      row_ptr = (int*)alloc((size_t)(n + 1) * 4);
  int*      colbuf  = (int*)alloc((size_t)e * 4);
  int*      bsum    = (int*)alloc((size_t)nb * 4);
  int*      boff    = (int*)alloc((size_t)nb * 4);
  float*    partial = (float*)alloc((size_t)256 * HID * 4);
  float*    mmf     = (float*)alloc(256);

  int b256 = 256;
  hipLaunchKernelGGL(k_tsmm, dim3(1), dim3(1024), 0, stream, ts, mmf, deg, n);
  hipLaunchKernelGGL(k_enc, dim3((n * 64 + 255) / 256), dim3(b256), 0, stream,
                     ts, freq, mmf, x, tfh, xh, n);
  hipLaunchKernelGGL(k_prep2, dim3(NB_QKV + NB_O + NB_B), dim3(b256), 0, stream,
                     qW, kW, vW, oW, qb, kb, vb, qkvWt, qkvb, oWt);
  hipLaunchKernelGGL(k_fold, dim3((65 * QKVW + 255) / 256), dim3(b256), 0, stream,
                     inW, inb, qW, kW, vW, qb, kb, vb, WcT, bc);
  hipLaunchKernelGGL(k_count, dim3((e + 255) / 256), dim3(b256), 0, stream, dst, deg, e);
  hipLaunchKernelGGL(k_scan_part, dim3(nb), dim3(b256), 0, stream, deg, bsum, n);
  hipLaunchKernelGGL(k_scan_mid, dim3(1), dim3(64), 0, stream, bsum, boff, nb);
  hipLaunchKernelGGL(k_scan_apply, dim3(nb), dim3(b256), 0, stream, deg, boff, row_ptr, cursor, n, e);
  hipLaunchKernelGGL(k_scatter, dim3((e + 255) / 256), dim3(b256), 0, stream, src, dst, row_ptr, cursor, colbuf, e);

  dim3 ggrid_h(HID / 64, (n + 127) / 128);
  int nchunks = (n + 63) / 64;
  for (int l = 0; l < NL; ++l) {
    const float*    qkvbl = qkvb + (size_t)l * QKVW;
    const _Float16* oWtl  = oWt + (size_t)l * HID * HID;
    if (l == 0) {
      hipLaunchKernelGGL(k_gemm_qkvp, dim3(qkv_grid), dim3(b256), 0, stream,
                         xh, 32, tfh, 32, WcT, bc, Qbuf, KV, n, 64, R);
    } else {
      const _Float16* qkvWtl = qkvWt + (size_t)l * QKVW * (HID + TD);
      hipLaunchKernelGGL(k_gemm_qkvp, dim3(qkv_grid), dim3(b256), 0, stream,
                         h, HID, tfh, TD, qkvWtl, qkvbl, Qbuf, KV, n, HID + TD, R);
    }
    hipLaunchKernelGGL(k_attn, dim3(nchunks * 8), dim3(b256), 0, stream,
                       Qbuf, KV, row_ptr, colbuf, ao, n);
    hipLaunchKernelGGL(k_gemm_f16, ggrid_h, dim3(b256), 0, stream,
                       ao, HID, ao, HID, oWtl, ob + l * HID, h, n, HID, HID, 1);
  }

  hipLaunchKernelGGL(k_pool_partial, dim3(256), dim3(b256), 0, stream, h, partial, n);
  hipLaunchKernelGGL(k_final, dim3(1), dim3(b256), 0, stream, partial, c1W, c1b, c2W, c2b, (float*)d_out, n);
}

// Round 17
// 466.263 us; speedup vs baseline: 1.0525x; 1.0337x over previous
//
#include <hip/hip_runtime.h>
#include <math.h>

#define HID 256
#define TD 32
#define NL 3
#define C1DIM 128
#define OUTDIM 2
#define QKVW 768

using half8  = __attribute__((ext_vector_type(8))) _Float16;
using half2v = __attribute__((ext_vector_type(2))) _Float16;
using f32x4  = __attribute__((ext_vector_type(4))) float;

typedef __attribute__((address_space(1))) void gbl_void_t;
typedef __attribute__((address_space(3))) void lds_void_t;

__device__ __forceinline__ void load16_to_lds(const void* g, void* l) {
  __builtin_amdgcn_global_load_lds((const gbl_void_t*)g, (lds_void_t*)l, 16, 0, 0);
}

__device__ __forceinline__ float dot8h(half8 a, half8 b, float acc) {
#if __has_builtin(__builtin_amdgcn_fdot2)
  union { half8 v; half2v h2[4]; } ua, ub;
  ua.v = a; ub.v = b;
#pragma unroll
  for (int j = 0; j < 4; ++j) acc = __builtin_amdgcn_fdot2(ua.h2[j], ub.h2[j], acc, false);
  return acc;
#else
#pragma unroll
  for (int j = 0; j < 8; ++j) acc += (float)a[j] * (float)b[j];
  return acc;
#endif
}

// ---------- setup: ts min/max (single block) + zero deg ----------
__global__ __launch_bounds__(1024) void k_tsmm(const float* __restrict__ ts,
                                               float* __restrict__ mmf,
                                               int* __restrict__ deg, int n) {
  int t = threadIdx.x;
  float lmin = INFINITY, lmax = -INFINITY;
  for (int i = t; i < n; i += 1024) {
    float v = ts[i];
    lmin = fminf(lmin, v);
    lmax = fmaxf(lmax, v);
    deg[i] = 0;
  }
#pragma unroll
  for (int off = 32; off >= 1; off >>= 1) {
    lmin = fminf(lmin, __shfl_xor(lmin, off));
    lmax = fmaxf(lmax, __shfl_xor(lmax, off));
  }
  __shared__ float wmin[16], wmax[16];
  int lane = t & 63, w = t >> 6;
  if (lane == 0) { wmin[w] = lmin; wmax[w] = lmax; }
  __syncthreads();
  if (t == 0) {
    float a = INFINITY, b = -INFINITY;
    for (int i = 0; i < 16; ++i) { a = fminf(a, wmin[i]); b = fmaxf(b, wmax[i]); }
    mmf[0] = a; mmf[1] = b;
  }
}

// ---------- merged time encoding + x conversion ----------
__global__ void k_enc(const float* __restrict__ ts, const float* __restrict__ freq,
                      const float* __restrict__ mmf, const float* __restrict__ x,
                      _Float16* __restrict__ tfh, _Float16* __restrict__ xh, int n) {
  int idx = blockIdx.x * blockDim.x + threadIdx.x;
  int nt = n * TD;
  if (idx < nt) {
    int node = idx >> 5, j = idx & 31;
    float t = (ts[node] - mmf[0]) / (mmf[1] - mmf[0] + 1e-8f);
    float w = t * freq[j & 15];
    tfh[idx] = (_Float16)((j < 16) ? cosf(w) : sinf(w));
  } else if (idx < nt + n * 32) {
    int i2 = idx - nt;
    xh[i2] = (_Float16)x[i2];
  }
}

// ---------- LDS-tiled weight prep (unpermuted): qkv + o transposes + bias ----------
#define NB_QKV (NL * 9 * 12)   // k-tiles 288/32 x n-tiles 768/64
#define NB_O   (NL * 8 * 4)    // 256/32 x 256/64
#define NB_B   9               // NL*768 / 256

__global__ __launch_bounds__(256) void k_prep2(
    const float* __restrict__ qW, const float* __restrict__ kW,
    const float* __restrict__ vW, const float* __restrict__ oW,
    const float* __restrict__ qb, const float* __restrict__ kb,
    const float* __restrict__ vb,
    _Float16* __restrict__ qkvWt, float* __restrict__ qkvb,
    _Float16* __restrict__ oWt) {
  __shared__ _Float16 lds[32][65];
  int bid = blockIdx.x;
  int t = threadIdx.x;
  const int KQ = HID + TD;  // 288

  if (bid < NB_QKV) {
    int l = bid / 108;
    int rem = bid - l * 108;
    int kt = rem / 12, ntile = rem - kt * 12;
    int k0 = kt * 32, n0 = ntile * 64;
#pragma unroll
    for (int it = 0; it < 8; ++it) {
      int i = it * 256 + t;
      int kk = i >> 6, nn = i & 63;
      int k = k0 + kk, nrow = n0 + nn;
      float v;
      if (nrow < 256)      v = qW[(size_t)l * KQ * HID + (size_t)k * HID + nrow];
      else if (nrow < 512) v = kW[(size_t)l * KQ * HID + (size_t)k * HID + (nrow - 256)];
      else                 v = (k < HID) ? vW[(size_t)l * HID * HID + (size_t)k * HID + (nrow - 512)] : 0.f;
      lds[kk][nn] = (_Float16)v;
    }
    __syncthreads();
    {
      int nn = t >> 2, kq = (t & 3) * 8;
      _Float16* dst = qkvWt + (size_t)l * QKVW * KQ + (size_t)(n0 + nn) * KQ + k0 + kq;
      half8 v;
#pragma unroll
      for (int j = 0; j < 8; ++j) v[j] = lds[kq + j][nn];
      *(half8*)dst = v;
    }
    return;
  }
  bid -= NB_QKV;

  if (bid < NB_O) {
    int l = bid / 32;
    int rem = bid - l * 32;
    int kt = rem / 4, ntile = rem - kt * 4;
    int k0 = kt * 32, n0 = ntile * 64;
#pragma unroll
    for (int it = 0; it < 8; ++it) {
      int i = it * 256 + t;
      int kk = i >> 6, nn = i & 63;
      lds[kk][nn] = (_Float16)oW[(size_t)l * HID * HID + (size_t)(k0 + kk) * HID + n0 + nn];
    }
    __syncthreads();
    {
      int nn = t >> 2, kq = (t & 3) * 8;
      _Float16* dst = oWt + (size_t)l * HID * HID + (size_t)(n0 + nn) * HID + k0 + kq;
      half8 v;
#pragma unroll
      for (int j = 0; j < 8; ++j) v[j] = lds[kq + j][nn];
      *(half8*)dst = v;
    }
    return;
  }
  bid -= NB_O;

  {
    int idx = bid * 256 + t;
    if (idx < NL * QKVW) {
      int l = idx / QKVW;
      int j = idx - l * QKVW;
      float v;
      if (j < 256)      v = qb[l * HID + j];
      else if (j < 512) v = kb[l * HID + (j - 256)];
      else              v = vb[l * HID + (j - 512)];
      qkvb[idx] = v;
    }
  }
}

// ---------- layer-0 fold: WcT[768][64] = [inW@W0_h ; W0_tf]^T, bc = qkvb0 + inb@W0_h ----------
__global__ __launch_bounds__(256) void k_fold(const float* __restrict__ inW,
                                              const float* __restrict__ inb,
                                              const float* __restrict__ qW,
                                              const float* __restrict__ kW,
                                              const float* __restrict__ vW,
                                              const float* __restrict__ qb,
                                              const float* __restrict__ kb,
                                              const float* __restrict__ vb,
                                              _Float16* __restrict__ WcT,
                                              float* __restrict__ bc) {
  int idx = blockIdx.x * 256 + threadIdx.x;
  if (idx >= 65 * QKVW) return;
  int j = idx / QKVW;
  int nrow = idx - j * QKVW;
  auto W0 = [&](int c, int nr) -> float {
    if (nr < 256)      return qW[(size_t)c * HID + nr];
    else if (nr < 512) return kW[(size_t)c * HID + (nr - 256)];
    else               return vW[(size_t)c * HID + (nr - 512)];
  };
  if (j < 32) {
    float acc = 0.f;
    for (int c = 0; c < 256; ++c) acc += inW[j * HID + c] * W0(c, nrow);
    WcT[(size_t)nrow * 64 + j] = (_Float16)acc;
  } else if (j < 64) {
    int r = 256 + (j - 32);
    float v = 0.f;
    if (nrow < 256)      v = qW[(size_t)r * HID + nrow];
    else if (nrow < 512) v = kW[(size_t)r * HID + (nrow - 256)];
    WcT[(size_t)nrow * 64 + j] = (_Float16)v;
  } else {
    float acc;
    if (nrow < 256)      acc = qb[nrow];
    else if (nrow < 512) acc = kb[nrow - 256];
    else                 acc = vb[nrow - 512];
    for (int c = 0; c < 256; ++c) acc += inb[c] * W0(c, nrow);
    bc[nrow] = acc;
  }
}

__global__ void k_count(const int* __restrict__ dst, int* deg, int e) {
  int i = blockIdx.x * blockDim.x + threadIdx.x;
  if (i < e) atomicAdd(&deg[dst[i]], 1);
}

// ---------- 3-kernel scan ----------
__global__ __launch_bounds__(256) void k_scan_part(const int* __restrict__ deg,
                                                   int* __restrict__ bsum, int n) {
  int t = threadIdx.x;
  int idx = blockIdx.x * 256 + t;
  int v = (idx < n) ? deg[idx] : 0;
  int lane = t & 63, w = t >> 6;
  int x = v;
#pragma unroll
  for (int off = 1; off < 64; off <<= 1) {
    int y = __shfl_up(x, off);
    if (lane >= off) x += y;
  }
  __shared__ int ws[4];
  if (lane == 63) ws[w] = x;
  __syncthreads();
  if (t == 0) bsum[blockIdx.x] = ws[0] + ws[1] + ws[2] + ws[3];
}

__global__ __launch_bounds__(64) void k_scan_mid(const int* __restrict__ bsum,
                                                 int* __restrict__ boff, int nb) {
  int lane = threadIdx.x;
  int carry = 0;
  for (int base = 0; base < nb; base += 64) {
    int i = base + lane;
    int v = (i < nb) ? bsum[i] : 0;
    int x = v;
#pragma unroll
    for (int off = 1; off < 64; off <<= 1) {
      int y = __shfl_up(x, off);
      if (lane >= off) x += y;
    }
    if (i < nb) boff[i] = carry + x - v;
    carry += __shfl(x, 63);
  }
}

__global__ __launch_bounds__(256) void k_scan_apply(const int* __restrict__ deg,
                                                    const int* __restrict__ boff,
                                                    int* __restrict__ row_ptr,
                                                    int* __restrict__ cursor, int n, int e) {
  int t = threadIdx.x;
  int idx = blockIdx.x * 256 + t;
  int v = (idx < n) ? deg[idx] : 0;
  int lane = t & 63, w = t >> 6;
  int x = v;
#pragma unroll
  for (int off = 1; off < 64; off <<= 1) {
    int y = __shfl_up(x, off);
    if (lane >= off) x += y;
  }
  __shared__ int ws[4];
  if (lane == 63) ws[w] = x;
  __syncthreads();
  int wpre = 0;
  for (int i = 0; i < w; ++i) wpre += ws[i];
  if (idx < n) {
    row_ptr[idx] = boff[blockIdx.x] + wpre + x - v;
    cursor[idx] = 0;
  }
  if (idx == 0) row_ptr[n] = e;
}

__global__ void k_scatter(const int* __restrict__ src, const int* __restrict__ dst,
                          const int* __restrict__ row_ptr, int* cursor,
                          int* __restrict__ colbuf, int e) {
  int i = blockIdx.x * blockDim.x + threadIdx.x;
  if (i >= e) return;
  int d = dst[i];
  int p = atomicAdd(&cursor[d], 1);
  colbuf[row_ptr[d] + p] = src[i];
}

// ---------- fp16 MFMA GEMM (128x64 tile, BK=32, 4 waves, double-buffered LDS) ----------
// mode 0: plain C write; mode 1: ELU C write; mode 2: QKV split write
// KV layout: KV[((h*M)+row)*64 + isV*32 + dim]  (_Float16; 128 B per (head,row))
__global__ __launch_bounds__(256) void k_gemm_f16(
    const _Float16* __restrict__ A1, int K1,
    const _Float16* __restrict__ A2, int K2,
    const _Float16* __restrict__ Bt,
    const float* __restrict__ bias,
    _Float16* __restrict__ C,
    _Float16* __restrict__ Qb,
    _Float16* __restrict__ KV,
    int M, int Ncols, int Ktot, int mode) {
  __shared__ half8 smem8[2 * 768];
  char* smem = (char*)smem8;
  const int tid = threadIdx.x;
  const int lane = tid & 63, wave = tid >> 6;
  const int wm = wave >> 1, wn = wave & 1;
  const int row0 = blockIdx.y * 128;
  const int col0 = blockIdx.x * 64;

  auto stage = [&](int buf, int k0) {
    char* sA = smem + buf * 12288;
    char* sB = sA + 8192;
#pragma unroll
    for (int i = 0; i < 2; ++i) {
      int kg = i * 2 + (wave >> 1);
      int row = (wave & 1) * 64 + lane;
      int grow = row0 + row; if (grow > M - 1) grow = M - 1;
      int k = k0 + kg * 8;
      const _Float16* src = (k < K1) ? (A1 + (size_t)grow * K1 + k)
                                     : (A2 + (size_t)grow * K2 + (k - K1));
      load16_to_lds(src, sA + (i * 256 + wave * 64) * 16);
    }
    {
      const _Float16* src = Bt + (size_t)(col0 + lane) * Ktot + k0 + wave * 8;
      load16_to_lds(src, sB + wave * 64 * 16);
    }
  };

  f32x4 acc[4][2];
#pragma unroll
  for (int mf = 0; mf < 4; ++mf)
#pragma unroll
    for (int nf = 0; nf < 2; ++nf) acc[mf][nf] = f32x4{0.f, 0.f, 0.f, 0.f};

  const int nsteps = Ktot >> 5;
  int cur = 0;
  stage(0, 0);
  __syncthreads();
  for (int st = 0; st < nsteps; ++st) {
    if (st + 1 < nsteps) stage(cur ^ 1, (st + 1) * 32);
    char* sA = smem + cur * 12288;
    char* sB = sA + 8192;
    half8 af[4], bf[2];
#pragma unroll
    for (int mf = 0; mf < 4; ++mf) {
      int slot = (lane >> 4) * 128 + wm * 64 + mf * 16 + (lane & 15);
      af[mf] = *(const half8*)(sA + slot * 16);
    }
#pragma unroll
    for (int nf = 0; nf < 2; ++nf) {
      int slot = (lane >> 4) * 64 + wn * 32 + nf * 16 + (lane & 15);
      bf[nf] = *(const half8*)(sB + slot * 16);
    }
#pragma unroll
    for (int mf = 0; mf < 4; ++mf)
#pragma unroll
      for (int nf = 0; nf < 2; ++nf)
        acc[mf][nf] = __builtin_amdgcn_mfma_f32_16x16x32_f16(af[mf], bf[nf], acc[mf][nf], 0, 0, 0);
    __syncthreads();
    cur ^= 1;
  }

  const int rbase = row0 + wm * 64 + (lane >> 4) * 4;
  const int cbase = col0 + wn * 32 + (lane & 15);
#pragma unroll
  for (int nf = 0; nf < 2; ++nf) {
    int col = cbase + nf * 16;
    float bv = bias[col];
    if (mode != 2) {
#pragma unroll
      for (int mf = 0; mf < 4; ++mf) {
#pragma unroll
        for (int r = 0; r < 4; ++r) {
          int row = rbase + mf * 16 + r;
          if (row < M) {
            float v = acc[mf][nf][r] + bv;
            if (mode == 1) v = (v > 0.f) ? v : expm1f(v);
            C[(size_t)row * Ncols + col] = (_Float16)v;
          }
        }
      }
    } else {
      bool isQ = col < 256;
      int cc = col - 256;
      int isV = cc >> 8;          // 0 = K, 1 = V (when !isQ)
      int c2 = cc & 255;
      int hh = c2 >> 5, dim = c2 & 31;
      size_t kvoff = ((size_t)hh * M) * 64 + isV * 32 + dim;
#pragma unroll
      for (int mf = 0; mf < 4; ++mf) {
#pragma unroll
        for (int r = 0; r < 4; ++r) {
          int row = rbase + mf * 16 + r;
          if (row < M) {
            float v = acc[mf][nf][r] + bv;
            if (isQ) Qb[(size_t)row * HID + col] = (_Float16)v;
            else     KV[kvoff + (size_t)row * 64] = (_Float16)v;
          }
        }
      }
    }
  }
}

// ---------- attention: head-split (L2-resident), fp16 K/V, 4 threads/node ----------
__global__ __launch_bounds__(256) void k_attn(const _Float16* __restrict__ Qb,
                                              const _Float16* __restrict__ KV,
                                              const int* __restrict__ row_ptr,
                                              const int* __restrict__ colbuf,
                                              _Float16* __restrict__ out, int n) {
  int h = blockIdx.x & 7;
  int node = (blockIdx.x >> 3) * 64 + (threadIdx.x >> 2);
  if (node >= n) return;
  int j = threadIdx.x & 3;   // dims j*8 .. j*8+7
  const float scale = 0.17677669529663687f;  // 1/sqrt(32)
  const _Float16* KVh = KV + ((size_t)h * n) * 64;

  half8 qh = *(const half8*)(Qb + (size_t)node * HID + h * 32 + j * 8);
  half8 qs;
#pragma unroll
  for (int q = 0; q < 8; ++q) qs[q] = (_Float16)((float)qh[q] * scale);

  int beg = row_ptr[node], end = row_ptr[node + 1];
  float m = -INFINITY, s = 0.f;
  float a[8] = {0.f, 0.f, 0.f, 0.f, 0.f, 0.f, 0.f, 0.f};

  for (int i = beg; i < end; i += 4) {
    half8 kk[4], vv[4];
#pragma unroll
    for (int t = 0; t < 4; ++t) {
      int ii = i + t; if (ii > end - 1) ii = end - 1;
      int sn = colbuf[ii];
      const _Float16* b = KVh + ((size_t)sn) * 64 + j * 8;
      kk[t] = *(const half8*)(b);
      vv[t] = *(const half8*)(b + 32);
    }
    float p[4];
#pragma unroll
    for (int t = 0; t < 4; ++t) p[t] = dot8h(qs, kk[t], 0.f);
#pragma unroll
    for (int t = 0; t < 4; ++t) {
      p[t] += __shfl_xor(p[t], 1);
      p[t] += __shfl_xor(p[t], 2);
      if (i + t >= end) p[t] = -INFINITY;  // tail mask (t=0 always real)
    }
#pragma unroll
    for (int t = 0; t < 4; ++t) {
      float sc_ = p[t];
      if (sc_ <= m) {
        float e2 = __expf(sc_ - m);
        s += e2;
#pragma unroll
        for (int q = 0; q < 8; ++q) a[q] = fmaf(e2, (float)vv[t][q], a[q]);
      } else {
        float f = __expf(m - sc_);  // m=-inf on first real edge -> f=0
        s = s * f + 1.f;
#pragma unroll
        for (int q = 0; q < 8; ++q) a[q] = fmaf(a[q], f, (float)vv[t][q]);
        m = sc_;
      }
    }
  }

  float inv = (s > 0.f) ? (1.f / s) : 0.f;
  half8 o;
#pragma unroll
  for (int q = 0; q < 8; ++q) o[q] = (_Float16)(a[q] * inv);
  *(half8*)(out + (size_t)node * HID + h * 32 + j * 8) = o;
}

// ---------- pooling + classifier ----------
__global__ __launch_bounds__(256) void k_pool_partial(const _Float16* __restrict__ h,
                                                      float* __restrict__ partial, int n) {
  int b = blockIdx.x, t = threadIdx.x;
  float s = 0.f;
  for (int r = b; r < n; r += 256) s += (float)h[(size_t)r * HID + t];
  partial[b * HID + t] = s;
}

__global__ __launch_bounds__(256) void k_final(const float* __restrict__ partial,
                                               const float* __restrict__ c1W,
                                               const float* __restrict__ c1b,
                                               const float* __restrict__ c2W,
                                               const float* __restrict__ c2b,
                                               float* __restrict__ out, int n) {
  __shared__ float gl[HID];
  __shared__ float r1[C1DIM];
  int t = threadIdx.x;
  float s = 0.f;
  for (int b = 0; b < 256; b++) s += partial[b * HID + t];
  gl[t] = s / (float)n;
  __syncthreads();
  if (t < C1DIM) {
    float a = c1b[t];
    for (int k = 0; k < HID; k++) a += gl[k] * c1W[k * C1DIM + t];
    r1[t] = fmaxf(a, 0.f);
  }
  __syncthreads();
  if (t < OUTDIM) {
    float a = c2b[t];
    for (int k = 0; k < C1DIM; k++) a += r1[k] * c2W[k * OUTDIM + t];
    out[t] = a;
  }
}

// ---------- host launcher ----------
extern "C" void kernel_launch(void* const* d_in, const int* in_sizes, int n_in,
                              void* d_out, int out_size, void* d_ws, size_t ws_size,
                              hipStream_t stream) {
  const float* x    = (const float*)d_in[0];
  const float* ts   = (const float*)d_in[1];
  const int*   ei   = (const int*)d_in[2];
  const float* freq = (const float*)d_in[4];
  const float* inW  = (const float*)d_in[5];
  const float* inb  = (const float*)d_in[6];
  const float* qW   = (const float*)d_in[7];
  const float* qb   = (const float*)d_in[8];
  const float* kW   = (const float*)d_in[9];
  const float* kb   = (const float*)d_in[10];
  const float* vW   = (const float*)d_in[11];
  const float* vb   = (const float*)d_in[12];
  const float* oW   = (const float*)d_in[13];
  const float* ob   = (const float*)d_in[14];
  const float* c1W  = (const float*)d_in[15];
  const float* c1b  = (const float*)d_in[16];
  const float* c2W  = (const float*)d_in[17];
  const float* c2b  = (const float*)d_in[18];

  int n = in_sizes[1];
  int e = in_sizes[2] / 2;
  const int* src = ei;
  const int* dst = ei + e;
  int nb = (n + 255) / 256;

  char* w = (char*)d_ws;
  size_t off = 0;
  auto alloc = [&](size_t bytes) -> char* {
    char* p = w + off;
    off = (off + bytes + 255) & ~(size_t)255;
    return p;
  };
  _Float16* tfh     = (_Float16*)alloc((size_t)n * TD * 2);
  _Float16* xh      = (_Float16*)alloc((size_t)n * 32 * 2);
  _Float16* h       = (_Float16*)alloc((size_t)n * HID * 2);
  _Float16* Qbuf    = (_Float16*)alloc((size_t)n * HID * 2);
  _Float16* KV      = (_Float16*)alloc((size_t)n * 512 * 2);  // 8 heads x 64 halves
  _Float16* ao      = (_Float16*)alloc((size_t)n * HID * 2);
  _Float16* qkvWt   = (_Float16*)alloc((size_t)NL * QKVW * (HID + TD) * 2);
  float*    qkvb    = (float*)alloc((size_t)NL * QKVW * 4);
  _Float16* oWt     = (_Float16*)alloc((size_t)NL * HID * HID * 2);
  _Float16* WcT     = (_Float16*)alloc((size_t)QKVW * 64 * 2);
  float*    bc      = (float*)alloc((size_t)QKVW * 4);
  int*      deg     = (int*)alloc((size_t)n * 4);
  int*      cursor  = (int*)alloc((size_t)n * 4);
  int*      row_ptr = (int*)alloc((size_t)(n + 1) * 4);
  int*      colbuf  = (int*)alloc((size_t)e * 4);
  int*      bsum    = (int*)alloc((size_t)nb * 4);
  int*      boff    = (int*)alloc((size_t)nb * 4);
  float*    partial = (float*)alloc((size_t)256 * HID * 4);
  float*    mmf     = (float*)alloc(256);

  int b256 = 256;
  hipLaunchKernelGGL(k_tsmm, dim3(1), dim3(1024), 0, stream, ts, mmf, deg, n);
  hipLaunchKernelGGL(k_enc, dim3((n * 64 + 255) / 256), dim3(b256), 0, stream,
                     ts, freq, mmf, x, tfh, xh, n);
  hipLaunchKernelGGL(k_prep2, dim3(NB_QKV + NB_O + NB_B), dim3(b256), 0, stream,
                     qW, kW, vW, oW, qb, kb, vb, qkvWt, qkvb, oWt);
  hipLaunchKernelGGL(k_fold, dim3((65 * QKVW + 255) / 256), dim3(b256), 0, stream,
                     inW, inb, qW, kW, vW, qb, kb, vb, WcT, bc);
  hipLaunchKernelGGL(k_count, dim3((e + 255) / 256), dim3(b256), 0, stream, dst, deg, e);
  hipLaunchKernelGGL(k_scan_part, dim3(nb), dim3(b256), 0, stream, deg, bsum, n);
  hipLaunchKernelGGL(k_scan_mid, dim3(1), dim3(64), 0, stream, bsum, boff, nb);
  hipLaunchKernelGGL(k_scan_apply, dim3(nb), dim3(b256), 0, stream, deg, boff, row_ptr, cursor, n, e);
  hipLaunchKernelGGL(k_scatter, dim3((e + 255) / 256), dim3(b256), 0, stream, src, dst, row_ptr, cursor, colbuf, e);

  dim3 ggrid_h(HID / 64, (n + 127) / 128);
  dim3 ggrid_qkv(QKVW / 64, (n + 127) / 128);
  int nchunks = (n + 63) / 64;
  for (int l = 0; l < NL; ++l) {
    const float*    qkvbl  = qkvb + (size_t)l * QKVW;
    const _Float16* oWtl   = oWt + (size_t)l * HID * HID;
    if (l == 0) {
      // folded: QKV0 = [x, tf] @ Wc + bc   (K = 64)
      hipLaunchKernelGGL(k_gemm_f16, ggrid_qkv, dim3(b256), 0, stream,
                         xh, 32, tfh, 32, WcT, bc, (_Float16*)nullptr, Qbuf, KV,
                         n, QKVW, 64, 2);
    } else {
      const _Float16* qkvWtl = qkvWt + (size_t)l * QKVW * (HID + TD);
      hipLaunchKernelGGL(k_gemm_f16, ggrid_qkv, dim3(b256), 0, stream,
                         h, HID, tfh, TD, qkvWtl, qkvbl, (_Float16*)nullptr, Qbuf, KV,
                         n, QKVW, HID + TD, 2);
    }
    hipLaunchKernelGGL(k_attn, dim3(nchunks * 8), dim3(b256), 0, stream,
                       Qbuf, KV, row_ptr, colbuf, ao, n);
    hipLaunchKernelGGL(k_gemm_f16, ggrid_h, dim3(b256), 0, stream,
                       ao, HID, ao, HID, oWtl, ob + l * HID, h, (_Float16*)nullptr, (_Float16*)nullptr,
                       n, HID, HID, 1);
  }

  hipLaunchKernelGGL(k_pool_partial, dim3(256), dim3(b256), 0, stream, h, partial, n);
  hipLaunchKernelGGL(k_final, dim3(1), dim3(b256), 0, stream, partial, c1W, c1b, c2W, c2b, (float*)d_out, n);
}

// Round 18
// 460.743 us; speedup vs baseline: 1.0651x; 1.0120x over previous
//
#include <hip/hip_runtime.h>
#include <math.h>

#define HID 256
#define TD 32
#define NL 3
#define C1DIM 128
#define OUTDIM 2
#define QKVW 768

using half8  = __attribute__((ext_vector_type(8))) _Float16;
using half4v = __attribute__((ext_vector_type(4))) _Float16;
using half2v = __attribute__((ext_vector_type(2))) _Float16;
using f32x4  = __attribute__((ext_vector_type(4))) float;

typedef __attribute__((address_space(1))) void gbl_void_t;
typedef __attribute__((address_space(3))) void lds_void_t;

__device__ __forceinline__ void load16_to_lds(const void* g, void* l) {
  __builtin_amdgcn_global_load_lds((const gbl_void_t*)g, (lds_void_t*)l, 16, 0, 0);
}

__device__ __forceinline__ float dot8h(half8 a, half8 b, float acc) {
#if __has_builtin(__builtin_amdgcn_fdot2)
  union { half8 v; half2v h2[4]; } ua, ub;
  ua.v = a; ub.v = b;
#pragma unroll
  for (int j = 0; j < 4; ++j) acc = __builtin_amdgcn_fdot2(ua.h2[j], ub.h2[j], acc, false);
  return acc;
#else
#pragma unroll
  for (int j = 0; j < 8; ++j) acc += (float)a[j] * (float)b[j];
  return acc;
#endif
}

// ---------- setup: ts min/max (single block) + zero deg ----------
__global__ __launch_bounds__(1024) void k_tsmm(const float* __restrict__ ts,
                                               float* __restrict__ mmf,
                                               int* __restrict__ deg, int n) {
  int t = threadIdx.x;
  float lmin = INFINITY, lmax = -INFINITY;
  for (int i = t; i < n; i += 1024) {
    float v = ts[i];
    lmin = fminf(lmin, v);
    lmax = fmaxf(lmax, v);
    deg[i] = 0;
  }
#pragma unroll
  for (int off = 32; off >= 1; off >>= 1) {
    lmin = fminf(lmin, __shfl_xor(lmin, off));
    lmax = fmaxf(lmax, __shfl_xor(lmax, off));
  }
  __shared__ float wmin[16], wmax[16];
  int lane = t & 63, w = t >> 6;
  if (lane == 0) { wmin[w] = lmin; wmax[w] = lmax; }
  __syncthreads();
  if (t == 0) {
    float a = INFINITY, b = -INFINITY;
    for (int i = 0; i < 16; ++i) { a = fminf(a, wmin[i]); b = fmaxf(b, wmax[i]); }
    mmf[0] = a; mmf[1] = b;
  }
}

// ---------- merged time encoding + x conversion ----------
__global__ void k_enc(const float* __restrict__ ts, const float* __restrict__ freq,
                      const float* __restrict__ mmf, const float* __restrict__ x,
                      _Float16* __restrict__ tfh, _Float16* __restrict__ xh, int n) {
  int idx = blockIdx.x * blockDim.x + threadIdx.x;
  int nt = n * TD;
  if (idx < nt) {
    int node = idx >> 5, j = idx & 31;
    float t = (ts[node] - mmf[0]) / (mmf[1] - mmf[0] + 1e-8f);
    float w = t * freq[j & 15];
    tfh[idx] = (_Float16)((j < 16) ? cosf(w) : sinf(w));
  } else if (idx < nt + n * 32) {
    int i2 = idx - nt;
    xh[i2] = (_Float16)x[i2];
  }
}

// ---------- merged weight prep (layers 1..2 qkv + all o transposes + biases) ----------
__global__ void k_prep(const float* __restrict__ qW,
                       const float* __restrict__ kW, const float* __restrict__ vW,
                       const float* __restrict__ oW, const float* __restrict__ qb,
                       const float* __restrict__ kb, const float* __restrict__ vb,
                       _Float16* __restrict__ qkvWt,
                       float* __restrict__ qkvb, _Float16* __restrict__ oWt) {
  int idx = blockIdx.x * blockDim.x + threadIdx.x;
  const int KQ = HID + TD;
  const int S1 = NL * QKVW * KQ;
  const int S2 = NL * QKVW;
  const int S3 = NL * HID * HID;
  if (idx < S1) {
    int l = idx / (QKVW * KQ);
    int rem = idx - l * (QKVW * KQ);
    int nrow = rem / KQ;
    int k = rem - nrow * KQ;
    float v;
    if (nrow < 256)      v = qW[(size_t)l * KQ * HID + (size_t)k * HID + nrow];
    else if (nrow < 512) v = kW[(size_t)l * KQ * HID + (size_t)k * HID + (nrow - 256)];
    else                 v = (k < HID) ? vW[(size_t)l * HID * HID + (size_t)k * HID + (nrow - 512)] : 0.f;
    qkvWt[idx] = (_Float16)v;
  } else if ((idx -= S1) < S2) {
    int l = idx / QKVW;
    int j = idx - l * QKVW;
    float v;
    if (j < 256)      v = qb[l * HID + j];
    else if (j < 512) v = kb[l * HID + (j - 256)];
    else              v = vb[l * HID + (j - 512)];
    qkvb[idx] = v;
  } else if ((idx -= S2) < S3) {
    int l = idx / (HID * HID);
    int rem = idx - l * (HID * HID);
    int nrow = rem / HID;
    int k = rem - nrow * HID;
    oWt[idx] = (_Float16)oW[(size_t)l * HID * HID + (size_t)k * HID + nrow];
  }
}

// ---------- layer-0 fold: WcT[768][64] = [inW@W0_h ; W0_tf]^T, bc = qkvb0 + inb@W0_h ----------
// j = idx/768 (0..64), nrow = idx%768. j<32: x-part dot; 32<=j<64: tf row copy; j==64: bias.
__global__ __launch_bounds__(256) void k_fold(const float* __restrict__ inW,
                                              const float* __restrict__ inb,
                                              const float* __restrict__ qW,
                                              const float* __restrict__ kW,
                                              const float* __restrict__ vW,
                                              const float* __restrict__ qb,
                                              const float* __restrict__ kb,
                                              const float* __restrict__ vb,
                                              _Float16* __restrict__ WcT,
                                              float* __restrict__ bc) {
  int idx = blockIdx.x * 256 + threadIdx.x;
  if (idx >= 65 * QKVW) return;
  int j = idx / QKVW;
  int nrow = idx - j * QKVW;
  auto W0 = [&](int c, int nr) -> float {
    if (nr < 256)      return qW[(size_t)c * HID + nr];
    else if (nr < 512) return kW[(size_t)c * HID + (nr - 256)];
    else               return vW[(size_t)c * HID + (nr - 512)];
  };
  if (j < 32) {
    float acc = 0.f;
    for (int c = 0; c < 256; ++c) acc += inW[j * HID + c] * W0(c, nrow);
    WcT[(size_t)nrow * 64 + j] = (_Float16)acc;
  } else if (j < 64) {
    int r = 256 + (j - 32);  // tf row in [256,288)
    float v = 0.f;
    if (nrow < 256)      v = qW[(size_t)r * HID + nrow];
    else if (nrow < 512) v = kW[(size_t)r * HID + (nrow - 256)];
    // v-part: tf rows don't feed V -> 0
    WcT[(size_t)nrow * 64 + j] = (_Float16)v;
  } else {
    float acc;
    if (nrow < 256)      acc = qb[nrow];
    else if (nrow < 512) acc = kb[nrow - 256];
    else                 acc = vb[nrow - 512];
    for (int c = 0; c < 256; ++c) acc += inb[c] * W0(c, nrow);
    bc[nrow] = acc;
  }
}

__global__ void k_count(const int* __restrict__ dst, int* deg, int e) {
  int i = blockIdx.x * blockDim.x + threadIdx.x;
  if (i < e) atomicAdd(&deg[dst[i]], 1);
}

// ---------- 3-kernel scan ----------
__global__ __launch_bounds__(256) void k_scan_part(const int* __restrict__ deg,
                                                   int* __restrict__ bsum, int n) {
  int t = threadIdx.x;
  int idx = blockIdx.x * 256 + t;
  int v = (idx < n) ? deg[idx] : 0;
  int lane = t & 63, w = t >> 6;
  int x = v;
#pragma unroll
  for (int off = 1; off < 64; off <<= 1) {
    int y = __shfl_up(x, off);
    if (lane >= off) x += y;
  }
  __shared__ int ws[4];
  if (lane == 63) ws[w] = x;
  __syncthreads();
  if (t == 0) bsum[blockIdx.x] = ws[0] + ws[1] + ws[2] + ws[3];
}

__global__ __launch_bounds__(64) void k_scan_mid(const int* __restrict__ bsum,
                                                 int* __restrict__ boff, int nb) {
  int lane = threadIdx.x;
  int carry = 0;
  for (int base = 0; base < nb; base += 64) {
    int i = base + lane;
    int v = (i < nb) ? bsum[i] : 0;
    int x = v;
#pragma unroll
    for (int off = 1; off < 64; off <<= 1) {
      int y = __shfl_up(x, off);
      if (lane >= off) x += y;
    }
    if (i < nb) boff[i] = carry + x - v;
    carry += __shfl(x, 63);
  }
}

__global__ __launch_bounds__(256) void k_scan_apply(const int* __restrict__ deg,
                                                    const int* __restrict__ boff,
                                                    int* __restrict__ row_ptr,
                                                    int* __restrict__ cursor, int n, int e) {
  int t = threadIdx.x;
  int idx = blockIdx.x * 256 + t;
  int v = (idx < n) ? deg[idx] : 0;
  int lane = t & 63, w = t >> 6;
  int x = v;
#pragma unroll
  for (int off = 1; off < 64; off <<= 1) {
    int y = __shfl_up(x, off);
    if (lane >= off) x += y;
  }
  __shared__ int ws[4];
  if (lane == 63) ws[w] = x;
  __syncthreads();
  int wpre = 0;
  for (int i = 0; i < w; ++i) wpre += ws[i];
  if (idx < n) {
    row_ptr[idx] = boff[blockIdx.x] + wpre + x - v;
    cursor[idx] = 0;
  }
  if (idx == 0) row_ptr[n] = e;
}

__global__ void k_scatter(const int* __restrict__ src, const int* __restrict__ dst,
                          const int* __restrict__ row_ptr, int* cursor,
                          int* __restrict__ colbuf, int e) {
  int i = blockIdx.x * blockDim.x + threadIdx.x;
  if (i >= e) return;
  int d = dst[i];
  int p = atomicAdd(&cursor[d], 1);
  colbuf[row_ptr[d] + p] = src[i];
}

// ---------- fp16 MFMA GEMM (128x64 tile, BK=32, 4 waves, double-buffered LDS) ----------
// mode 0: plain C write; mode 1: ELU C write; mode 2: QKV split write
// KV layout: KV[((h*M)+row)*64 + isV*32 + dim]  (_Float16; 128 B per (head,row))
__global__ __launch_bounds__(256) void k_gemm_f16(
    const _Float16* __restrict__ A1, int K1,
    const _Float16* __restrict__ A2, int K2,
    const _Float16* __restrict__ Bt,
    const float* __restrict__ bias,
    _Float16* __restrict__ C,
    _Float16* __restrict__ Qb,
    _Float16* __restrict__ KV,
    int M, int Ncols, int Ktot, int mode) {
  __shared__ half8 smem8[2 * 768];
  char* smem = (char*)smem8;
  const int tid = threadIdx.x;
  const int lane = tid & 63, wave = tid >> 6;
  const int wm = wave >> 1, wn = wave & 1;
  const int row0 = blockIdx.y * 128;
  const int col0 = blockIdx.x * 64;

  auto stage = [&](int buf, int k0) {
    char* sA = smem + buf * 12288;
    char* sB = sA + 8192;
#pragma unroll
    for (int i = 0; i < 2; ++i) {
      int kg = i * 2 + (wave >> 1);
      int row = (wave & 1) * 64 + lane;
      int grow = row0 + row; if (grow > M - 1) grow = M - 1;
      int k = k0 + kg * 8;
      const _Float16* src = (k < K1) ? (A1 + (size_t)grow * K1 + k)
                                     : (A2 + (size_t)grow * K2 + (k - K1));
      load16_to_lds(src, sA + (i * 256 + wave * 64) * 16);
    }
    {
      const _Float16* src = Bt + (size_t)(col0 + lane) * Ktot + k0 + wave * 8;
      load16_to_lds(src, sB + wave * 64 * 16);
    }
  };

  f32x4 acc[4][2];
#pragma unroll
  for (int mf = 0; mf < 4; ++mf)
#pragma unroll
    for (int nf = 0; nf < 2; ++nf) acc[mf][nf] = f32x4{0.f, 0.f, 0.f, 0.f};

  const int nsteps = Ktot >> 5;
  int cur = 0;
  stage(0, 0);
  __syncthreads();
  for (int st = 0; st < nsteps; ++st) {
    if (st + 1 < nsteps) stage(cur ^ 1, (st + 1) * 32);
    char* sA = smem + cur * 12288;
    char* sB = sA + 8192;
    half8 af[4], bf[2];
#pragma unroll
    for (int mf = 0; mf < 4; ++mf) {
      int slot = (lane >> 4) * 128 + wm * 64 + mf * 16 + (lane & 15);
      af[mf] = *(const half8*)(sA + slot * 16);
    }
#pragma unroll
    for (int nf = 0; nf < 2; ++nf) {
      int slot = (lane >> 4) * 64 + wn * 32 + nf * 16 + (lane & 15);
      bf[nf] = *(const half8*)(sB + slot * 16);
    }
#pragma unroll
    for (int mf = 0; mf < 4; ++mf)
#pragma unroll
      for (int nf = 0; nf < 2; ++nf)
        acc[mf][nf] = __builtin_amdgcn_mfma_f32_16x16x32_f16(af[mf], bf[nf], acc[mf][nf], 0, 0, 0);
    __syncthreads();
    cur ^= 1;
  }

  const int rbase = row0 + wm * 64 + (lane >> 4) * 4;
  const int cbase = col0 + wn * 32 + (lane & 15);
#pragma unroll
  for (int nf = 0; nf < 2; ++nf) {
    int col = cbase + nf * 16;
    float bv = bias[col];
    if (mode != 2) {
#pragma unroll
      for (int mf = 0; mf < 4; ++mf) {
#pragma unroll
        for (int r = 0; r < 4; ++r) {
          int row = rbase + mf * 16 + r;
          if (row < M) {
            float v = acc[mf][nf][r] + bv;
            if (mode == 1) v = (v > 0.f) ? v : expm1f(v);
            C[(size_t)row * Ncols + col] = (_Float16)v;
          }
        }
      }
    } else {
      bool isQ = col < 256;
      int cc = col - 256;
      int isV = cc >> 8;          // 0 = K, 1 = V (when !isQ)
      int c2 = cc & 255;
      int hh = c2 >> 5, dim = c2 & 31;
      size_t kvoff = ((size_t)hh * M) * 64 + isV * 32 + dim;
#pragma unroll
      for (int mf = 0; mf < 4; ++mf) {
#pragma unroll
        for (int r = 0; r < 4; ++r) {
          int row = rbase + mf * 16 + r;
          if (row < M) {
            float v = acc[mf][nf][r] + bv;
            if (isQ) Qb[(size_t)row * HID + col] = (_Float16)v;
            else     KV[kvoff + (size_t)row * 64] = (_Float16)v;
          }
        }
      }
    }
  }
}

// ---------- attention: head-split (L2-resident), fp16 K/V, 4 threads/node ----------
// head = blockIdx.x & 7 (XCD round-robin); 64 nodes/block, 4 threads/node (8 dims each)
__global__ __launch_bounds__(256) void k_attn(const _Float16* __restrict__ Qb,
                                              const _Float16* __restrict__ KV,
                                              const int* __restrict__ row_ptr,
                                              const int* __restrict__ colbuf,
                                              _Float16* __restrict__ out, int n) {
  int h = blockIdx.x & 7;
  int node = (blockIdx.x >> 3) * 64 + (threadIdx.x >> 2);
  if (node >= n) return;
  int j = threadIdx.x & 3;   // dims j*8 .. j*8+7
  const float scale = 0.17677669529663687f;  // 1/sqrt(32)
  const _Float16* KVh = KV + ((size_t)h * n) * 64;

  half8 qh = *(const half8*)(Qb + (size_t)node * HID + h * 32 + j * 8);
  half8 qs;
#pragma unroll
  for (int q = 0; q < 8; ++q) qs[q] = (_Float16)((float)qh[q] * scale);

  int beg = row_ptr[node], end = row_ptr[node + 1];
  float m = -INFINITY, s = 0.f;
  float a[8] = {0.f, 0.f, 0.f, 0.f, 0.f, 0.f, 0.f, 0.f};

  for (int i = beg; i < end; i += 4) {
    half8 kk[4], vv[4];
#pragma unroll
    for (int t = 0; t < 4; ++t) {
      int ii = i + t; if (ii > end - 1) ii = end - 1;
      int sn = colbuf[ii];
      const _Float16* b = KVh + ((size_t)sn) * 64 + j * 8;
      kk[t] = *(const half8*)(b);
      vv[t] = *(const half8*)(b + 32);
    }
    float p[4];
#pragma unroll
    for (int t = 0; t < 4; ++t) p[t] = dot8h(qs, kk[t], 0.f);
#pragma unroll
    for (int t = 0; t < 4; ++t) {
      p[t] += __shfl_xor(p[t], 1);
      p[t] += __shfl_xor(p[t], 2);
      if (i + t >= end) p[t] = -INFINITY;  // tail mask (t=0 always real)
    }
#pragma unroll
    for (int t = 0; t < 4; ++t) {
      float sc_ = p[t];
      if (sc_ <= m) {
        float e2 = __expf(sc_ - m);
        s += e2;
#pragma unroll
        for (int q = 0; q < 8; ++q) a[q] = fmaf(e2, (float)vv[t][q], a[q]);
      } else {
        float f = __expf(m - sc_);  // m=-inf on first real edge -> f=0
        s = s * f + 1.f;
#pragma unroll
        for (int q = 0; q < 8; ++q) a[q] = fmaf(a[q], f, (float)vv[t][q]);
        m = sc_;
      }
    }
  }

  float inv = (s > 0.f) ? (1.f / s) : 0.f;
  half8 o;
#pragma unroll
  for (int q = 0; q < 8; ++q) o[q] = (_Float16)(a[q] * inv);
  *(half8*)(out + (size_t)node * HID + h * 32 + j * 8) = o;
}

// ---------- pooling + classifier ----------
__global__ __launch_bounds__(256) void k_pool_partial(const _Float16* __restrict__ h,
                                                      float* __restrict__ partial, int n) {
  int b = blockIdx.x, t = threadIdx.x;
  float s = 0.f;
  for (int r = b; r < n; r += 256) s += (float)h[(size_t)r * HID + t];
  partial[b * HID + t] = s;
}

__global__ __launch_bounds__(256) void k_final(const float* __restrict__ partial,
                                               const float* __restrict__ c1W,
                                               const float* __restrict__ c1b,
                                               const float* __restrict__ c2W,
                                               const float* __restrict__ c2b,
                                               float* __restrict__ out, int n) {
  __shared__ float gl[HID];
  __shared__ float r1[C1DIM];
  int t = threadIdx.x;
  float s = 0.f;
  for (int b = 0; b < 256; b++) s += partial[b * HID + t];
  gl[t] = s / (float)n;
  __syncthreads();
  if (t < C1DIM) {
    float a = c1b[t];
    for (int k = 0; k < HID; k++) a += gl[k] * c1W[k * C1DIM + t];
    r1[t] = fmaxf(a, 0.f);
  }
  __syncthreads();
  if (t < OUTDIM) {
    float a = c2b[t];
    for (int k = 0; k < C1DIM; k++) a += r1[k] * c2W[k * OUTDIM + t];
    out[t] = a;
  }
}

// ---------- host launcher ----------
extern "C" void kernel_launch(void* const* d_in, const int* in_sizes, int n_in,
                              void* d_out, int out_size, void* d_ws, size_t ws_size,
                              hipStream_t stream) {
  const float* x    = (const float*)d_in[0];
  const float* ts   = (const float*)d_in[1];
  const int*   ei   = (const int*)d_in[2];
  const float* freq = (const float*)d_in[4];
  const float* inW  = (const float*)d_in[5];
  const float* inb  = (const float*)d_in[6];
  const float* qW   = (const float*)d_in[7];
  const float* qb   = (const float*)d_in[8];
  const float* kW   = (const float*)d_in[9];
  const float* kb   = (const float*)d_in[10];
  const float* vW   = (const float*)d_in[11];
  const float* vb   = (const float*)d_in[12];
  const float* oW   = (const float*)d_in[13];
  const float* ob   = (const float*)d_in[14];
  const float* c1W  = (const float*)d_in[15];
  const float* c1b  = (const float*)d_in[16];
  const float* c2W  = (const float*)d_in[17];
  const float* c2b  = (const float*)d_in[18];

  int n = in_sizes[1];
  int e = in_sizes[2] / 2;
  const int* src = ei;
  const int* dst = ei + e;
  int nb = (n + 255) / 256;

  char* w = (char*)d_ws;
  size_t off = 0;
  auto alloc = [&](size_t bytes) -> char* {
    char* p = w + off;
    off = (off + bytes + 255) & ~(size_t)255;
    return p;
  };
  _Float16* tfh     = (_Float16*)alloc((size_t)n * TD * 2);
  _Float16* xh      = (_Float16*)alloc((size_t)n * 32 * 2);
  _Float16* h       = (_Float16*)alloc((size_t)n * HID * 2);
  _Float16* Qbuf    = (_Float16*)alloc((size_t)n * HID * 2);
  _Float16* KV      = (_Float16*)alloc((size_t)n * 512 * 2);  // 8 heads x 64 halves
  _Float16* ao      = (_Float16*)alloc((size_t)n * HID * 2);
  _Float16* qkvWt   = (_Float16*)alloc((size_t)NL * QKVW * (HID + TD) * 2);
  float*    qkvb    = (float*)alloc((size_t)NL * QKVW * 4);
  _Float16* oWt     = (_Float16*)alloc((size_t)NL * HID * HID * 2);
  _Float16* WcT     = (_Float16*)alloc((size_t)QKVW * 64 * 2);
  float*    bc      = (float*)alloc((size_t)QKVW * 4);
  int*      deg     = (int*)alloc((size_t)n * 4);
  int*      cursor  = (int*)alloc((size_t)n * 4);
  int*      row_ptr = (int*)alloc((size_t)(n + 1) * 4);
  int*      colbuf  = (int*)alloc((size_t)e * 4);
  int*      bsum    = (int*)alloc((size_t)nb * 4);
  int*      boff    = (int*)alloc((size_t)nb * 4);
  float*    partial = (float*)alloc((size_t)256 * HID * 4);
  float*    mmf     = (float*)alloc(256);

  int b256 = 256;
  hipLaunchKernelGGL(k_tsmm, dim3(1), dim3(1024), 0, stream, ts, mmf, deg, n);
  hipLaunchKernelGGL(k_enc, dim3((n * 64 + 255) / 256), dim3(b256), 0, stream,
                     ts, freq, mmf, x, tfh, xh, n);
  {
    int total = NL * QKVW * (HID + TD) + NL * QKVW + NL * HID * HID;
    hipLaunchKernelGGL(k_prep, dim3((total + 255) / 256), dim3(b256), 0, stream,
                       qW, kW, vW, oW, qb, kb, vb, qkvWt, qkvb, oWt);
  }
  hipLaunchKernelGGL(k_fold, dim3((65 * QKVW + 255) / 256), dim3(b256), 0, stream,
                     inW, inb, qW, kW, vW, qb, kb, vb, WcT, bc);
  hipLaunchKernelGGL(k_count, dim3((e + 255) / 256), dim3(b256), 0, stream, dst, deg, e);
  hipLaunchKernelGGL(k_scan_part, dim3(nb), dim3(b256), 0, stream, deg, bsum, n);
  hipLaunchKernelGGL(k_scan_mid, dim3(1), dim3(64), 0, stream, bsum, boff, nb);
  hipLaunchKernelGGL(k_scan_apply, dim3(nb), dim3(b256), 0, stream, deg, boff, row_ptr, cursor, n, e);
  hipLaunchKernelGGL(k_scatter, dim3((e + 255) / 256), dim3(b256), 0, stream, src, dst, row_ptr, cursor, colbuf, e);

  dim3 ggrid_h(HID / 64, (n + 127) / 128);
  dim3 ggrid_qkv(QKVW / 64, (n + 127) / 128);
  int nchunks = (n + 63) / 64;
  for (int l = 0; l < NL; ++l) {
    const float*    qkvbl  = qkvb + (size_t)l * QKVW;
    const _Float16* oWtl   = oWt + (size_t)l * HID * HID;
    if (l == 0) {
      // folded: QKV0 = [x, tf] @ Wc + bc   (K = 64)
      hipLaunchKernelGGL(k_gemm_f16, ggrid_qkv, dim3(b256), 0, stream,
                         xh, 32, tfh, 32, WcT, bc, (_Float16*)nullptr, Qbuf, KV,
                         n, QKVW, 64, 2);
    } else {
      const _Float16* qkvWtl = qkvWt + (size_t)l * QKVW * (HID + TD);
      hipLaunchKernelGGL(k_gemm_f16, ggrid_qkv, dim3(b256), 0, stream,
                         h, HID, tfh, TD, qkvWtl, qkvbl, (_Float16*)nullptr, Qbuf, KV,
                         n, QKVW, HID + TD, 2);
    }
    hipLaunchKernelGGL(k_attn, dim3(nchunks * 8), dim3(b256), 0, stream,
                       Qbuf, KV, row_ptr, colbuf, ao, n);
    hipLaunchKernelGGL(k_gemm_f16, ggrid_h, dim3(b256), 0, stream,
                       ao, HID, ao, HID, oWtl, ob + l * HID, h, (_Float16*)nullptr, (_Float16*)nullptr,
                       n, HID, HID, 1);
  }

  hipLaunchKernelGGL(k_pool_partial, dim3(256), dim3(b256), 0, stream, h, partial, n);
  hipLaunchKernelGGL(k_final, dim3(1), dim3(b256), 0, stream, partial, c1W, c1b, c2W, c2b, (float*)d_out, n);
}